// Round 1
// baseline (326.303 us; speedup 1.0000x reference)
//
#include <hip/hip_runtime.h>
#include <hip/hip_bf16.h>

#define HIDN   64
#define NHEADS 8
#define DHEAD  8
#define NLAY   2
#define BB     4
#define SS     12
#define NNODE  512
#define NEDGE  8192
#define XELEMS (BB * SS * NNODE * 3)      // 73728
#define ROWS   (BB * SS * NNODE)          // 24576
#define QSCALE 0.51006967f                // (1/sqrt(8)) * log2(e): exp(x)=exp2(x*log2e)
#define PSTR   36                         // P row stride u16; MUST be mult of 4 (b64 align)

typedef unsigned short u16;
typedef unsigned int   u32;
typedef __attribute__((ext_vector_type(8))) short s8v;   // 8 bf16 (4 VGPRs)
typedef __attribute__((ext_vector_type(4))) float f4v;   // MFMA C/D

__device__ __forceinline__ float b2f(u16 u) {
    union { u32 i; float f; } c; c.i = ((u32)u) << 16; return c.f;
}
__device__ __forceinline__ u16 f2b(float f) {   // RNE float->bf16 bits
    union { float f; u32 i; } c; c.f = f;
    u32 r = c.i + 0x7FFFu + ((c.i >> 16) & 1u);
    return (u16)(r >> 16);
}
// decode element i of a raw input tensor (fl=1 -> fp32, fl=0 -> bf16)
__device__ __forceinline__ float ld(const void* p, int i, int fl) {
    return fl ? ((const float*)p)[i] : b2f(((const u16*)p)[i]);
}
// v_cvt_pk_bf16_f32: lo16=bf16(a), hi16=bf16(b), RNE (gfx950-verified)
__device__ __forceinline__ u32 cvtpk_bf16(float a, float b) {
    u32 r;
    asm("v_cvt_pk_bf16_f32 %0, %1, %2" : "=v"(r) : "v"(a), "v"(b));
    return r;
}

// -------- dtype detection FALLBACK (only if in_sizes is ambiguous):
// bf16 buffer decoded as bf16 has max|v|~4.5; fp32 halves decoded as bf16
// hit |v|>1e30 / NaN w.p. ~1.
__global__ void detect_kernel(const u16* __restrict__ x, int* __restrict__ flag) {
    int i0 = blockIdx.x * 256 + threadIdx.x;
    int bad = 0;
    for (int i = i0; i < XELEMS; i += 64 * 256) {
        float v = fabsf(b2f(x[i]));
        if (!(v <= 100.f)) bad = 1;   // catches huge AND NaN
    }
    if (bad) atomicOr(flag, 1);       // flag=1 -> inputs are fp32
}

// ---------------- pack W[l][j][i] (RAW input, decoded) -> wT[l][i][192], bias[l][192]
// grid (48, L, 2): z=0 spatial set, z=1 temporal set. Replaces convert+2 packs.
struct PackArgs {
    const void* Wq[2]; const void* bq[2];
    const void* Wk[2]; const void* bk[2];
    const void* Wv[2]; const void* bv[2];
    float* wT[2]; float* bp[2];
};
__global__ void pack_kernel(PackArgs a, const int* __restrict__ flagp) {
    int fl = (*flagp != 0);
    int p = blockIdx.z;
    int l = blockIdx.y;
    int t = blockIdx.x * 256 + threadIdx.x;   // 0..12287
    int i = t / 192, j = t - i * 192;
    int c = j >> 6, cc = j & 63;
    const void* W = (c == 0) ? a.Wq[p] : (c == 1) ? a.Wk[p] : a.Wv[p];
    a.wT[p][l * 12288 + t] = ld(W, l * 4096 + cc * 64 + i, fl);
    if (i == 0) {
        const void* B = (c == 0) ? a.bq[p] : (c == 1) ? a.bk[p] : a.bv[p];
        a.bp[p][l * 192 + j] = ld(B, l * 64 + cc, fl);
    }
}

// ---------------- edge mask, transposed bitmask: maskT[n][m>>5] bit (m&31) ---
__global__ void scatter_mask_kernel(const int* __restrict__ ei, u32* __restrict__ maskT) {
    int e = blockIdx.x * blockDim.x + threadIdx.x;
    if (e < NEDGE) {
        int n = ei[e];          // query row
        int m = ei[NEDGE + e];  // key col
        atomicOr(&maskT[n * 16 + (m >> 5)], 1u << (m & 31));
    }
}

// ---------------- input projection: raw x [B,S,N,3] @ raw WinT + b -> h [ROWS,64]
__global__ void input_proj_kernel(const void* __restrict__ x, const void* __restrict__ W,
                                  const void* __restrict__ b, float* __restrict__ h,
                                  const int* __restrict__ flagp) {
    int fl = (*flagp != 0);
    int t = blockIdx.x * blockDim.x + threadIdx.x;  // row*64 + j
    int row = t >> 6, j = t & 63;
    float x0 = ld(x, row * 3, fl);
    float x1 = ld(x, row * 3 + 1, fl);
    float x2 = ld(x, row * 3 + 2, fl);
    h[t] = ld(b, j, fl) + x0 * ld(W, j * 3, fl) + x1 * ld(W, j * 3 + 1, fl)
                        + x2 * ld(W, j * 3 + 2, fl);
}

// ---------------- fused q/k/v GEMM (fp32 VALU, high-TLP) ---------------------
// block: 32 rows x 192 cols, 256 threads, 2x12 acc/thread, grid 768 = 3 blk/CU.
// spatial_layout=1: q/k/v BF16 [bs*8+hd][n][8]; q prescaled by (1/sqrt8)*log2e.
// spatial_layout=0: q/k/v fp32 row-major [row][64].
__global__ __launch_bounds__(256) void qkv_gemm_kernel(
    const float* __restrict__ h, const float* __restrict__ wT,
    const float* __restrict__ bias,
    float* __restrict__ q, float* __restrict__ k, float* __restrict__ v,
    u16* __restrict__ qb16, u16* __restrict__ kb16, u16* __restrict__ vb16,
    int spatial_layout) {
    __shared__ float hT[64][36];    // [i][r], 32 rows + pad
    __shared__ float wS[32][192];   // [i-half][j]
    __shared__ float bS[192];
    int t = threadIdx.x;
    int row0 = blockIdx.x * 32;
    // stage A transposed: 32 rows x 64 i (each thread: 1 row, 8 i)
    {
        int r = t & 31, ic = t >> 5;        // ic 0..7 -> i0 = ic*8
        const float* hp = h + (row0 + r) * 64 + ic * 8;
        float4 h0 = *(const float4*)hp;
        float4 h1 = *(const float4*)(hp + 4);
        int i = ic * 8;
        hT[i+0][r] = h0.x; hT[i+1][r] = h0.y; hT[i+2][r] = h0.z; hT[i+3][r] = h0.w;
        hT[i+4][r] = h1.x; hT[i+5][r] = h1.y; hT[i+6][r] = h1.z; hT[i+7][r] = h1.w;
    }
    // stage W phase 0 + bias
    {
        const float4* src = (const float4*)wT;
        float4* dst = (float4*)&wS[0][0];
#pragma unroll
        for (int c = 0; c < 6; ++c) dst[t + 256 * c] = src[t + 256 * c];
        if (t < 192) bS[t] = bias[t];
    }
    __syncthreads();
    int tc = t & 15, tr = t >> 4;
    int r0 = tc * 2, j0 = tr * 12;
    float acc[12][2];
#pragma unroll
    for (int j = 0; j < 12; ++j) {
        float bb = bS[j0 + j];
        acc[j][0] = bb; acc[j][1] = bb;
    }
#pragma unroll 4
    for (int i = 0; i < 32; ++i) {
        float2 a = *(const float2*)&hT[i][r0];
#pragma unroll
        for (int jj = 0; jj < 3; ++jj) {
            float4 w = *(const float4*)&wS[i][j0 + jj * 4];
            int jb = jj * 4;
            acc[jb+0][0] += w.x*a.x; acc[jb+0][1] += w.x*a.y;
            acc[jb+1][0] += w.y*a.x; acc[jb+1][1] += w.y*a.y;
            acc[jb+2][0] += w.z*a.x; acc[jb+2][1] += w.z*a.y;
            acc[jb+3][0] += w.w*a.x; acc[jb+3][1] += w.w*a.y;
        }
    }
    __syncthreads();
    // stage W phase 1
    {
        const float4* src = (const float4*)(wT + 32 * 192);
        float4* dst = (float4*)&wS[0][0];
#pragma unroll
        for (int c = 0; c < 6; ++c) dst[t + 256 * c] = src[t + 256 * c];
    }
    __syncthreads();
#pragma unroll 4
    for (int i = 0; i < 32; ++i) {
        float2 a = *(const float2*)&hT[32 + i][r0];
#pragma unroll
        for (int jj = 0; jj < 3; ++jj) {
            float4 w = *(const float4*)&wS[i][j0 + jj * 4];
            int jb = jj * 4;
            acc[jb+0][0] += w.x*a.x; acc[jb+0][1] += w.x*a.y;
            acc[jb+1][0] += w.y*a.x; acc[jb+1][1] += w.y*a.y;
            acc[jb+2][0] += w.z*a.x; acc[jb+2][1] += w.z*a.y;
            acc[jb+3][0] += w.w*a.x; acc[jb+3][1] += w.w*a.y;
        }
    }
    // epilogue
#pragma unroll
    for (int j = 0; j < 12; ++j) {
        int jj = j0 + j;
        int cc = jj & 63;
#pragma unroll
        for (int r = 0; r < 2; ++r) {
            int row = row0 + r0 + r;
            float val = acc[j][r];
            if (spatial_layout) {
                int bs = row >> 9, n = row & 511;
                int idx = ((bs * 8 + (cc >> 3)) * 512 + n) * 8 + (cc & 7);
                if (jj < 64)       qb16[idx] = f2b(val * QSCALE);
                else if (jj < 128) kb16[idx] = f2b(val);
                else               vb16[idx] = f2b(val);
            } else {
                int idx = row * 64 + cc;
                float* dst = (jj < 64) ? q : (jj < 128) ? k : v;
                dst[idx] = val;
            }
        }
    }
}

// ---------------- spatial attention v8: MFMA flash, exp2 + cvt_pk ------------
// grid 768 = (bs,hd,half); 256 threads (4 waves); wave owns 64 queries.
// S^T = K.Q^T (16x16x32 bf16); q prescaled by (1/sqrt8)*log2e so
// P = exp2(S) (single v_exp_f32); masked -> -inf -> exactly 0.
// P pack via v_cvt_pk_bf16_f32 (replaces 3-op RNE + perm).
// O = P.[V|1] gives l in col 8 free.
__global__ __launch_bounds__(256) void spatial_attn_kernel(
    const u16* __restrict__ qb, const u16* __restrict__ kb, const u16* __restrict__ vb,
    const u32* __restrict__ maskT, float* __restrict__ h) {
    __shared__ __align__(16) u16 Ks[NNODE * 8];      // [key][d]  8 KB
    __shared__ __align__(16) u16 Vs[9 * 520];        // [d|ones][key] stride 520
    __shared__ __align__(16) u32 Ms[16 * 256];       // [word][qlocal]  16 KB
    __shared__ __align__(16) u16 Pb[4][64 * PSTR];   // per-wave P [q][key] stride 36
    int bx = blockIdx.x;               // head*2 + half
    int head = bx >> 1, half = bx & 1;
    int bs = head >> 3, hd = head & 7;
    int base = head * (NNODE * 8);
    int t = threadIdx.x;
    // stage K rows
    {
        const uint4* kg = (const uint4*)(kb + base);
        uint4* kl = (uint4*)Ks;
        kl[t] = kg[t];
        kl[t + 256] = kg[t + 256];
    }
    // stage V transposed + ones row
    {
#pragma unroll
        for (int i = 0; i < 2; ++i) {
            int n = t + 256 * i;
            uint4 vr = *(const uint4*)(vb + base + n * 8);
            union { uint4 u; u16 s[8]; } V; V.u = vr;
#pragma unroll
            for (int d = 0; d < 8; ++d) Vs[d * 520 + n] = V.s[d];
            Vs[8 * 520 + n] = 0x3F80;   // 1.0bf16
        }
    }
    // stage mask transposed: Ms[w][n] = maskT[(half*256+n)*16 + w]
    {
        int qg0 = half * 256;
#pragma unroll
        for (int i = 0; i < 16; ++i) {
            int idx = t + 256 * i;      // 0..4095
            int n = idx >> 4, w = idx & 15;
            Ms[w * 256 + n] = maskT[(qg0 + n) * 16 + w];
        }
    }
    __syncthreads();
    int lane = t & 63;
    int wave = t >> 6;
    int c    = lane & 15;
    int quad = lane >> 4;
    int qloc0  = wave * 64;
    int qglob0 = half * 256 + qloc0;
    // Q fragments (B): lanes<16 hold Q[q][0..7]
    s8v Qf[4];
#pragma unroll
    for (int qt = 0; qt < 4; ++qt) {
        union { s8v v; uint4 u; } U; U.u = make_uint4(0, 0, 0, 0);
        if (lane < 16) U.u = *(const uint4*)(qb + base + (qglob0 + qt * 16 + lane) * 8);
        Qf[qt] = U.v;
    }
    f4v acc[4];
#pragma unroll
    for (int qt = 0; qt < 4; ++qt) acc[qt] = (f4v){0.f, 0.f, 0.f, 0.f};
    u16* Pw = &Pb[wave][0];
    const float NINF = -__builtin_inff();
    for (int it = 0; it < 16; ++it) {
        int k0 = it * 32;
        s8v Kf[2];
#pragma unroll
        for (int kt = 0; kt < 2; ++kt) {
            union { s8v v; uint4 u; } U; U.u = make_uint4(0, 0, 0, 0);
            if (lane < 16) U.u = *(const uint4*)&Ks[(k0 + kt * 16 + lane) * 8];
            Kf[kt] = U.v;
        }
        union { s8v v; uint4 u; } Vu; Vu.u = make_uint4(0, 0, 0, 0);
        if (c <= 8) Vu.u = *(const uint4*)&Vs[c * 520 + k0 + quad * 8];
#pragma unroll
        for (int qt = 0; qt < 4; ++qt) {
            // pre-shift by quad*4: bits {kt*16+0..3} select this thread's keys
            u32 wq = Ms[it * 256 + qloc0 + qt * 16 + c] >> (quad * 4);
            int rbase = (qt * 16 + c) * PSTR;
#pragma unroll
            for (int kt = 0; kt < 2; ++kt) {
                f4v S = __builtin_amdgcn_mfma_f32_16x16x32_bf16(
                    Kf[kt], Qf[qt], (f4v){0.f, 0.f, 0.f, 0.f}, 0, 0, 0);
                float e[4];
#pragma unroll
                for (int reg = 0; reg < 4; ++reg) {
                    float sm = ((wq >> (kt * 16 + reg)) & 1u) ? S[reg] : NINF;
                    e[reg] = exp2f(sm);   // single v_exp_f32; exp2(-inf)=0
                }
                u32 p0 = cvtpk_bf16(e[0], e[1]);
                u32 p1 = cvtpk_bf16(e[2], e[3]);
                *(uint2*)&Pw[rbase + kt * 16 + quad * 4] = make_uint2(p0, p1);
            }
        }
        __builtin_amdgcn_sched_barrier(0);   // keep P writes before A reads
#pragma unroll
        for (int qt = 0; qt < 4; ++qt) {
            int row = (qt * 16 + c) * PSTR;
            uint2 lo = *(const uint2*)&Pw[row + quad * 8];
            uint2 hi = *(const uint2*)&Pw[row + quad * 8 + 4];
            union { s8v v; uint4 u; } A; A.u = make_uint4(lo.x, lo.y, hi.x, hi.y);
            acc[qt] = __builtin_amdgcn_mfma_f32_16x16x32_bf16(A.v, Vu.v, acc[qt], 0, 0, 0);
        }
    }
    // epilogue: l lives in column 8; broadcast through per-wave LDS
    float* lb = (float*)Pw;   // 256 B reuse
    if (c == 8) {
#pragma unroll
        for (int qt = 0; qt < 4; ++qt)
#pragma unroll
            for (int reg = 0; reg < 4; ++reg)
                lb[qt * 16 + quad * 4 + reg] = acc[qt][reg];
    }
    __builtin_amdgcn_sched_barrier(0);
    if (c < 8) {
#pragma unroll
        for (int qt = 0; qt < 4; ++qt) {
#pragma unroll
            for (int reg = 0; reg < 4; ++reg) {
                int row = qt * 16 + quad * 4 + reg;
                float lv = lb[row];
                float o  = acc[qt][reg];
                if (lv == 0.f) {   // fully-masked row: uniform mean(v)
                    float s = 0.f;
                    for (int m = 0; m < NNODE; ++m) s += b2f(Vs[c * 520 + m]);
                    o = s; lv = (float)NNODE;
                }
                h[(bs * 512 + qglob0 + row) * 64 + hd * 8 + c] = o / lv;
            }
        }
    }
}

// ---------------- temporal attention: thread per (b,s,n,h), loop t (S=12) ----
// q/k dot prescaled by (1/sqrt8)*log2e -> exp2f (single v_exp_f32).
__global__ __launch_bounds__(256) void temporal_attn_kernel(
    const float* __restrict__ q, const float* __restrict__ k, const float* __restrict__ v,
    float* __restrict__ h) {
    int t    = blockIdx.x * blockDim.x + threadIdx.x;
    int hd   = t & 7;
    int n    = (t >> 3) & (NNODE - 1);
    int rest = t >> 12;  // b*S + sq
    int b    = rest / SS;
    const float* qp = q + (rest * NNODE + n) * HIDN + hd * DHEAD;
    float4 qa = *(const float4*)qp;
    float4 qc = *(const float4*)(qp + 4);
    const float* kbase = k + (b * SS * NNODE + n) * HIDN + hd * DHEAD;
    const float* vbase = v + (b * SS * NNODE + n) * HIDN + hd * DHEAD;
    float s[SS];
#pragma unroll
    for (int tt = 0; tt < SS; ++tt) {
        const float* kp = kbase + tt * (NNODE * HIDN);
        float4 ka = *(const float4*)kp;
        float4 kc = *(const float4*)(kp + 4);
        s[tt] = (qa.x * ka.x + qa.y * ka.y + qa.z * ka.z + qa.w * ka.w +
                 qc.x * kc.x + qc.y * kc.y + qc.z * kc.z + qc.w * kc.w) * QSCALE;
    }
    float mx = s[0];
#pragma unroll
    for (int tt = 1; tt < SS; ++tt) mx = fmaxf(mx, s[tt]);
    float l = 0.f;
#pragma unroll
    for (int tt = 0; tt < SS; ++tt) { s[tt] = exp2f(s[tt] - mx); l += s[tt]; }
    float a0 = 0.f, a1 = 0.f, a2 = 0.f, a3 = 0.f, a4 = 0.f, a5 = 0.f, a6 = 0.f, a7 = 0.f;
#pragma unroll
    for (int tt = 0; tt < SS; ++tt) {
        const float* vp = vbase + tt * (NNODE * HIDN);
        float4 va = *(const float4*)vp;
        float4 vc = *(const float4*)(vp + 4);
        float e = s[tt];
        a0 += e * va.x; a1 += e * va.y; a2 += e * va.z; a3 += e * va.w;
        a4 += e * vc.x; a5 += e * vc.y; a6 += e * vc.z; a7 += e * vc.w;
    }
    float inv = 1.f / l;
    float* op = h + (rest * NNODE + n) * HIDN + hd * DHEAD;
    *(float4*)op       = make_float4(a0 * inv, a1 * inv, a2 * inv, a3 * inv);
    *(float4*)(op + 4) = make_float4(a4 * inv, a5 * inv, a6 * inv, a7 * inv);
}

// ---------------- output projection: h[:, S-1] @ raw WoutT + raw bout --------
__global__ void out_proj_kernel(const float* __restrict__ h, const void* __restrict__ W,
                                const void* __restrict__ b, void* __restrict__ out,
                                const int* __restrict__ flagp) {
    int fl = (*flagp != 0);
    int t = blockIdx.x * blockDim.x + threadIdx.x;
    if (t >= BB * NNODE * 3) return;
    int c  = t % 3;
    int bn = t / 3;
    int n  = bn & (NNODE - 1);
    int bb = bn >> 9;
    const float* hp = h + ((bb * SS + (SS - 1)) * NNODE + n) * HIDN;
    float a = ld(b, c, fl);
#pragma unroll
    for (int i = 0; i < HIDN; i += 4) {
        float4 h4 = *(const float4*)(hp + i);
        a += h4.x * ld(W, c * 64 + i,     fl) + h4.y * ld(W, c * 64 + i + 1, fl)
           + h4.z * ld(W, c * 64 + i + 2, fl) + h4.w * ld(W, c * 64 + i + 3, fl);
    }
    if (fl) ((float*)out)[t] = a;
    else    ((__hip_bfloat16*)out)[t] = __float2bfloat16(a);
}

extern "C" void kernel_launch(void* const* d_in, const int* in_sizes, int n_in,
                              void* d_out, int out_size, void* d_ws, size_t ws_size,
                              hipStream_t stream) {
    const int* ei = (const int*)d_in[1];

    float* ws = (float*)d_ws;
    int*   flag  = (int*)ws;               // 64 floats reserved
    u32*   maskT = (u32*)(ws + 64);        // 8192 u32
    float* wTs   = ws + 64 + 8192;         // 2*12288
    float* wTt   = wTs + 24576;            // 2*12288
    float* bsp   = wTt + 24576;            // 2*192
    float* btp   = bsp + 384;              // 2*192
    float* hbuf  = btp + 384;              // ROWS*64 each
    float* qbuf  = hbuf + ROWS * HIDN;
    float* kbuf  = qbuf + ROWS * HIDN;
    float* vbuf  = kbuf + ROWS * HIDN;
    u16*   qb16  = (u16*)qbuf;             // alias: spatial q bf16 (prescaled)
    u16*   kb16  = (u16*)kbuf;             // alias: spatial K bf16
    u16*   vb16  = (u16*)vbuf;             // alias: spatial V bf16
    // total ws use ~25.4 MB

    // dtype from host-visible byte sizes; runtime-detect only if ambiguous
    int flv = -1;
    if (in_sizes) {
        if (in_sizes[0] == XELEMS * 2) flv = 0;        // bf16
        else if (in_sizes[0] == XELEMS * 4) flv = 1;   // fp32
    }
    if (flv >= 0) {
        (void)hipMemsetAsync(flag, flv, sizeof(int), stream);  // bytes 0 or 0x01010101 (nonzero)
    } else {
        (void)hipMemsetAsync(flag, 0, sizeof(int), stream);
        detect_kernel<<<64, 256, 0, stream>>>((const u16*)d_in[0], flag);
    }
    (void)hipMemsetAsync(maskT, 0, 8192 * sizeof(u32), stream);
    scatter_mask_kernel<<<NEDGE / 256, 256, 0, stream>>>(ei, maskT);

    PackArgs pa;
    pa.Wq[0] = d_in[4];  pa.bq[0] = d_in[5];
    pa.Wk[0] = d_in[6];  pa.bk[0] = d_in[7];
    pa.Wv[0] = d_in[8];  pa.bv[0] = d_in[9];
    pa.Wq[1] = d_in[10]; pa.bq[1] = d_in[11];
    pa.Wk[1] = d_in[12]; pa.bk[1] = d_in[13];
    pa.Wv[1] = d_in[14]; pa.bv[1] = d_in[15];
    pa.wT[0] = wTs; pa.bp[0] = bsp;
    pa.wT[1] = wTt; pa.bp[1] = btp;
    pack_kernel<<<dim3(48, NLAY, 2), 256, 0, stream>>>(pa, flag);

    input_proj_kernel<<<ROWS * HIDN / 256, 256, 0, stream>>>(
        d_in[0], d_in[2], d_in[3], hbuf, flag);

    const int GEMM_BLOCKS = ROWS / 32;                       // 768
    const int ATTN_BLOCKS = BB * SS * NHEADS * NNODE / 256;  // 768 (temporal)
    for (int l = 0; l < NLAY; ++l) {
        // spatial
        qkv_gemm_kernel<<<GEMM_BLOCKS, 256, 0, stream>>>(
            hbuf, wTs + l * 12288, bsp + l * 192, qbuf, kbuf, vbuf,
            qb16, kb16, vb16, 1);
        spatial_attn_kernel<<<BB * SS * NHEADS * 2, 256, 0, stream>>>(
            qb16, kb16, vb16, maskT, hbuf);
        // temporal
        qkv_gemm_kernel<<<GEMM_BLOCKS, 256, 0, stream>>>(
            hbuf, wTt + l * 12288, btp + l * 192, qbuf, kbuf, vbuf,
            qb16, kb16, vb16, 0);
        temporal_attn_kernel<<<ATTN_BLOCKS, 256, 0, stream>>>(qbuf, kbuf, vbuf, hbuf);
    }
    out_proj_kernel<<<(BB * NNODE * 3 + 255) / 256, 256, 0, stream>>>(
        hbuf, d_in[16], d_in[17], d_out, flag);
}

// Round 2
// 318.171 us; speedup vs baseline: 1.0256x; 1.0256x over previous
//
#include <hip/hip_runtime.h>
#include <hip/hip_bf16.h>

#define HIDN   64
#define NHEADS 8
#define DHEAD  8
#define NLAY   2
#define BB     4
#define SS     12
#define NNODE  512
#define NEDGE  8192
#define XELEMS (BB * SS * NNODE * 3)      // 73728
#define ROWS   (BB * SS * NNODE)          // 24576
#define QSCALE 0.51006967f                // (1/sqrt(8)) * log2(e): exp(x)=exp2(x*log2e)

typedef unsigned short u16;
typedef unsigned int   u32;
typedef __attribute__((ext_vector_type(8))) short s8v;   // 8 bf16 (4 VGPRs)
typedef __attribute__((ext_vector_type(4))) float f4v;   // MFMA C/D

__device__ __forceinline__ float b2f(u16 u) {
    union { u32 i; float f; } c; c.i = ((u32)u) << 16; return c.f;
}
__device__ __forceinline__ u16 f2b(float f) {   // RNE float->bf16 bits
    union { float f; u32 i; } c; c.f = f;
    u32 r = c.i + 0x7FFFu + ((c.i >> 16) & 1u);
    return (u16)(r >> 16);
}
// decode element i of a raw input tensor (fl=1 -> fp32, fl=0 -> bf16)
__device__ __forceinline__ float ld(const void* p, int i, int fl) {
    return fl ? ((const float*)p)[i] : b2f(((const u16*)p)[i]);
}
// v_cvt_pk_bf16_f32: lo16=bf16(a), hi16=bf16(b), RNE (gfx950-verified)
__device__ __forceinline__ u32 cvtpk_bf16(float a, float b) {
    u32 r;
    asm("v_cvt_pk_bf16_f32 %0, %1, %2" : "=v"(r) : "v"(a), "v"(b));
    return r;
}

// -------- dtype detection FALLBACK (only if in_sizes is ambiguous) -----------
__global__ void detect_kernel(const u16* __restrict__ x, int* __restrict__ flag) {
    int i0 = blockIdx.x * 256 + threadIdx.x;
    int bad = 0;
    for (int i = i0; i < XELEMS; i += 64 * 256) {
        float v = fabsf(b2f(x[i]));
        if (!(v <= 100.f)) bad = 1;   // catches huge AND NaN
    }
    if (bad) atomicOr(flag, 1);       // flag=1 -> inputs are fp32
}

// ---------------- pack W[l][j][i] (RAW input, decoded) -> wT[l][i][192], bias[l][192]
struct PackArgs {
    const void* Wq[2]; const void* bq[2];
    const void* Wk[2]; const void* bk[2];
    const void* Wv[2]; const void* bv[2];
    float* wT[2]; float* bp[2];
};
__global__ void pack_kernel(PackArgs a, const int* __restrict__ flagp) {
    int fl = (*flagp != 0);
    int p = blockIdx.z;
    int l = blockIdx.y;
    int t = blockIdx.x * 256 + threadIdx.x;   // 0..12287
    int i = t / 192, j = t - i * 192;
    int c = j >> 6, cc = j & 63;
    const void* W = (c == 0) ? a.Wq[p] : (c == 1) ? a.Wk[p] : a.Wv[p];
    a.wT[p][l * 12288 + t] = ld(W, l * 4096 + cc * 64 + i, fl);
    if (i == 0) {
        const void* B = (c == 0) ? a.bq[p] : (c == 1) ? a.bk[p] : a.bv[p];
        a.bp[p][l * 192 + j] = ld(B, l * 64 + cc, fl);
    }
}

// ---------------- edge mask, transposed bitmask: maskT[n][m>>5] bit (m&31) ---
__global__ void scatter_mask_kernel(const int* __restrict__ ei, u32* __restrict__ maskT) {
    int e = blockIdx.x * blockDim.x + threadIdx.x;
    if (e < NEDGE) {
        int n = ei[e];          // query row
        int m = ei[NEDGE + e];  // key col
        atomicOr(&maskT[n * 16 + (m >> 5)], 1u << (m & 31));
    }
}

// ---------------- input projection: raw x [B,S,N,3] @ raw WinT + b -> h [ROWS,64]
__global__ void input_proj_kernel(const void* __restrict__ x, const void* __restrict__ W,
                                  const void* __restrict__ b, float* __restrict__ h,
                                  const int* __restrict__ flagp) {
    int fl = (*flagp != 0);
    int t = blockIdx.x * blockDim.x + threadIdx.x;  // row*64 + j
    int row = t >> 6, j = t & 63;
    float x0 = ld(x, row * 3, fl);
    float x1 = ld(x, row * 3 + 1, fl);
    float x2 = ld(x, row * 3 + 2, fl);
    h[t] = ld(b, j, fl) + x0 * ld(W, j * 3, fl) + x1 * ld(W, j * 3 + 1, fl)
                        + x2 * ld(W, j * 3 + 2, fl);
}

// ---------------- fused q/k/v GEMM (fp32 VALU, high-TLP) ---------------------
__global__ __launch_bounds__(256) void qkv_gemm_kernel(
    const float* __restrict__ h, const float* __restrict__ wT,
    const float* __restrict__ bias,
    float* __restrict__ q, float* __restrict__ k, float* __restrict__ v,
    u16* __restrict__ qb16, u16* __restrict__ kb16, u16* __restrict__ vb16,
    int spatial_layout) {
    __shared__ float hT[64][36];    // [i][r], 32 rows + pad
    __shared__ float wS[32][192];   // [i-half][j]
    __shared__ float bS[192];
    int t = threadIdx.x;
    int row0 = blockIdx.x * 32;
    {
        int r = t & 31, ic = t >> 5;        // ic 0..7 -> i0 = ic*8
        const float* hp = h + (row0 + r) * 64 + ic * 8;
        float4 h0 = *(const float4*)hp;
        float4 h1 = *(const float4*)(hp + 4);
        int i = ic * 8;
        hT[i+0][r] = h0.x; hT[i+1][r] = h0.y; hT[i+2][r] = h0.z; hT[i+3][r] = h0.w;
        hT[i+4][r] = h1.x; hT[i+5][r] = h1.y; hT[i+6][r] = h1.z; hT[i+7][r] = h1.w;
    }
    {
        const float4* src = (const float4*)wT;
        float4* dst = (float4*)&wS[0][0];
#pragma unroll
        for (int c = 0; c < 6; ++c) dst[t + 256 * c] = src[t + 256 * c];
        if (t < 192) bS[t] = bias[t];
    }
    __syncthreads();
    int tc = t & 15, tr = t >> 4;
    int r0 = tc * 2, j0 = tr * 12;
    float acc[12][2];
#pragma unroll
    for (int j = 0; j < 12; ++j) {
        float bb = bS[j0 + j];
        acc[j][0] = bb; acc[j][1] = bb;
    }
#pragma unroll 4
    for (int i = 0; i < 32; ++i) {
        float2 a = *(const float2*)&hT[i][r0];
#pragma unroll
        for (int jj = 0; jj < 3; ++jj) {
            float4 w = *(const float4*)&wS[i][j0 + jj * 4];
            int jb = jj * 4;
            acc[jb+0][0] += w.x*a.x; acc[jb+0][1] += w.x*a.y;
            acc[jb+1][0] += w.y*a.x; acc[jb+1][1] += w.y*a.y;
            acc[jb+2][0] += w.z*a.x; acc[jb+2][1] += w.z*a.y;
            acc[jb+3][0] += w.w*a.x; acc[jb+3][1] += w.w*a.y;
        }
    }
    __syncthreads();
    {
        const float4* src = (const float4*)(wT + 32 * 192);
        float4* dst = (float4*)&wS[0][0];
#pragma unroll
        for (int c = 0; c < 6; ++c) dst[t + 256 * c] = src[t + 256 * c];
    }
    __syncthreads();
#pragma unroll 4
    for (int i = 0; i < 32; ++i) {
        float2 a = *(const float2*)&hT[32 + i][r0];
#pragma unroll
        for (int jj = 0; jj < 3; ++jj) {
            float4 w = *(const float4*)&wS[i][j0 + jj * 4];
            int jb = jj * 4;
            acc[jb+0][0] += w.x*a.x; acc[jb+0][1] += w.x*a.y;
            acc[jb+1][0] += w.y*a.x; acc[jb+1][1] += w.y*a.y;
            acc[jb+2][0] += w.z*a.x; acc[jb+2][1] += w.z*a.y;
            acc[jb+3][0] += w.w*a.x; acc[jb+3][1] += w.w*a.y;
        }
    }
#pragma unroll
    for (int j = 0; j < 12; ++j) {
        int jj = j0 + j;
        int cc = jj & 63;
#pragma unroll
        for (int r = 0; r < 2; ++r) {
            int row = row0 + r0 + r;
            float val = acc[j][r];
            if (spatial_layout) {
                int bs = row >> 9, n = row & 511;
                int idx = ((bs * 8 + (cc >> 3)) * 512 + n) * 8 + (cc & 7);
                if (jj < 64)       qb16[idx] = f2b(val * QSCALE);
                else if (jj < 128) kb16[idx] = f2b(val);
                else               vb16[idx] = f2b(val);
            } else {
                int idx = row * 64 + cc;
                float* dst = (jj < 64) ? q : (jj < 128) ? k : v;
                dst[idx] = val;
            }
        }
    }
}

// ---------------- spatial attention v9: P stays in registers -----------------
// grid 768 = (bs,hd,half); 256 threads (4 waves); wave owns 64 queries.
// S^T = K.Q^T (16x16x32 bf16, swapped operands): thread (c,quad) holds P for
// QUERY c, keys {quad*4+r (kt0), 16+quad*4+r (kt1)}. V is staged in LDS with
// key order permuted to pos = 8*quad + 4*kt + r, so the packed exp2 results
// ARE the PV A-fragment (A[row=c][k=quad*8+j]) -- no P LDS round trip.
// Mask words re-laid-out so the 4 qt words per thread are one ds_read_b128.
// O = P.[V|1] gives l in pos-col 8 (ones row) free.
__global__ __launch_bounds__(256) void spatial_attn_kernel(
    const u16* __restrict__ qb, const u16* __restrict__ kb, const u16* __restrict__ vb,
    const u32* __restrict__ maskT, float* __restrict__ h) {
    __shared__ __align__(16) u16 Ks[NNODE * 8];      // [key][d]  8 KB (original order)
    __shared__ __align__(16) u16 Vs[9 * 520];        // [d|ones][pos] stride 520, permuted
    __shared__ __align__(16) u32 Ms[16 * 256];       // [it][qloc0 | c*4+qt]  16 KB
    __shared__ float lb[4][64];                      // per-wave l broadcast
    int bx = blockIdx.x;               // head*2 + half
    int head = bx >> 1, half = bx & 1;
    int bs = head >> 3, hd = head & 7;
    int base = head * (NNODE * 8);
    int t = threadIdx.x;
    // stage K rows (original key order)
    {
        const uint4* kg = (const uint4*)(kb + base);
        uint4* kl = (uint4*)Ks;
        kl[t] = kg[t];
        kl[t + 256] = kg[t + 256];
    }
    // stage V transposed + ones row, key order PERMUTED within each 32-tile:
    // pos(o) = ((o&12)<<1) | (o&3) | ((o>>4)<<2)   (bijective)
    {
#pragma unroll
        for (int i = 0; i < 2; ++i) {
            int n = t + 256 * i;
            int o = n & 31;
            int pos = ((o & 12) << 1) | (o & 3) | ((o >> 4) << 2);
            int col = (n & ~31) + pos;
            uint4 vr = *(const uint4*)(vb + base + n * 8);
            union { uint4 u; u16 s[8]; } V; V.u = vr;
#pragma unroll
            for (int d = 0; d < 8; ++d) Vs[d * 520 + col] = V.s[d];
            Vs[8 * 520 + col] = 0x3F80;   // 1.0 bf16
        }
    }
    // stage mask: thread t owns qlocal=t; Ms[it*256 + (t&0xC0) + (t&15)*4 + ((t>>4)&3)]
    {
        int qg0 = half * 256;
        int wbase = (t & 0xC0) | ((t & 15) << 2) | ((t >> 4) & 3);
        const u32* mp = maskT + (qg0 + t) * 16;
#pragma unroll
        for (int g = 0; g < 4; ++g) {
            uint4 m4 = *(const uint4*)(mp + g * 4);
            Ms[(g * 4 + 0) * 256 + wbase] = m4.x;
            Ms[(g * 4 + 1) * 256 + wbase] = m4.y;
            Ms[(g * 4 + 2) * 256 + wbase] = m4.z;
            Ms[(g * 4 + 3) * 256 + wbase] = m4.w;
        }
    }
    __syncthreads();
    int lane = t & 63;
    int wave = t >> 6;
    int c    = lane & 15;
    int quad = lane >> 4;
    int cv   = (c < 9) ? c : 8;          // clamp V col read (cols 9..15 unused)
    int qloc0  = wave * 64;
    int qglob0 = half * 256 + qloc0;
    // Q fragments (B operand): lanes<16 hold Q[q][0..7]; rest ZERO (k>=8 dead)
    s8v Qf[4];
#pragma unroll
    for (int qt = 0; qt < 4; ++qt) {
        union { s8v v; uint4 u; } U; U.u = make_uint4(0, 0, 0, 0);
        if (lane < 16) U.u = *(const uint4*)(qb + base + (qglob0 + qt * 16 + lane) * 8);
        Qf[qt] = U.v;
    }
    f4v acc[4];
#pragma unroll
    for (int qt = 0; qt < 4; ++qt) acc[qt] = (f4v){0.f, 0.f, 0.f, 0.f};
    const float NINF = -__builtin_inff();
    for (int it = 0; it < 16; ++it) {
        int k0 = it * 32;
        // K fragments: UNCONDITIONAL (Q is zero at k>=8, so lanes>=16 are don't-care)
        s8v Kf0, Kf1;
        {
            union { s8v v; uint4 u; } U;
            U.u = *(const uint4*)&Ks[(k0 + c) * 8];      Kf0 = U.v;
            U.u = *(const uint4*)&Ks[(k0 + 16 + c) * 8]; Kf1 = U.v;
        }
        union { s8v v; uint4 u; } Vu;
        Vu.u = *(const uint4*)&Vs[cv * 520 + k0 + quad * 8];
        uint4 wv = *(const uint4*)&Ms[it * 256 + qloc0 + (c << 2)];
        u32 wqa[4] = {wv.x, wv.y, wv.z, wv.w};
#pragma unroll
        for (int qt = 0; qt < 4; ++qt) {
            u32 wq = wqa[qt] >> (quad * 4);   // bits {kt*16 + 0..3}
            f4v S0 = __builtin_amdgcn_mfma_f32_16x16x32_bf16(
                Kf0, Qf[qt], (f4v){0.f, 0.f, 0.f, 0.f}, 0, 0, 0);
            f4v S1 = __builtin_amdgcn_mfma_f32_16x16x32_bf16(
                Kf1, Qf[qt], (f4v){0.f, 0.f, 0.f, 0.f}, 0, 0, 0);
            float e0[4], e1[4];
#pragma unroll
            for (int r = 0; r < 4; ++r) {
                e0[r] = exp2f(((wq >> r) & 1u)        ? S0[r] : NINF);
                e1[r] = exp2f(((wq >> (16 + r)) & 1u) ? S1[r] : NINF);
            }
            // packed exp2 results == PV A-fragment (positions quad*8 + 0..7)
            union { s8v v; uint4 u; } A;
            A.u = make_uint4(cvtpk_bf16(e0[0], e0[1]), cvtpk_bf16(e0[2], e0[3]),
                             cvtpk_bf16(e1[0], e1[1]), cvtpk_bf16(e1[2], e1[3]));
            acc[qt] = __builtin_amdgcn_mfma_f32_16x16x32_bf16(A.v, Vu.v, acc[qt], 0, 0, 0);
        }
    }
    // epilogue: l lives in V-col 8 (ones row); broadcast through per-wave LDS
    if (c == 8) {
#pragma unroll
        for (int qt = 0; qt < 4; ++qt)
#pragma unroll
            for (int reg = 0; reg < 4; ++reg)
                lb[wave][qt * 16 + quad * 4 + reg] = acc[qt][reg];
    }
    __builtin_amdgcn_sched_barrier(0);
    if (c < 8) {
#pragma unroll
        for (int qt = 0; qt < 4; ++qt) {
#pragma unroll
            for (int reg = 0; reg < 4; ++reg) {
                int row = qt * 16 + quad * 4 + reg;
                float lv = lb[wave][row];
                float o  = acc[qt][reg];
                if (lv == 0.f) {   // fully-masked row: uniform mean(v) (perm-invariant sum)
                    float s = 0.f;
                    for (int m = 0; m < NNODE; ++m) s += b2f(Vs[c * 520 + m]);
                    o = s; lv = (float)NNODE;
                }
                h[(bs * 512 + qglob0 + row) * 64 + hd * 8 + c] = o / lv;
            }
        }
    }
}

// ---------------- temporal attention: thread per (b,s,n,h), loop t (S=12) ----
__global__ __launch_bounds__(256) void temporal_attn_kernel(
    const float* __restrict__ q, const float* __restrict__ k, const float* __restrict__ v,
    float* __restrict__ h) {
    int t    = blockIdx.x * blockDim.x + threadIdx.x;
    int hd   = t & 7;
    int n    = (t >> 3) & (NNODE - 1);
    int rest = t >> 12;  // b*S + sq
    int b    = rest / SS;
    const float* qp = q + (rest * NNODE + n) * HIDN + hd * DHEAD;
    float4 qa = *(const float4*)qp;
    float4 qc = *(const float4*)(qp + 4);
    const float* kbase = k + (b * SS * NNODE + n) * HIDN + hd * DHEAD;
    const float* vbase = v + (b * SS * NNODE + n) * HIDN + hd * DHEAD;
    float s[SS];
#pragma unroll
    for (int tt = 0; tt < SS; ++tt) {
        const float* kp = kbase + tt * (NNODE * HIDN);
        float4 ka = *(const float4*)kp;
        float4 kc = *(const float4*)(kp + 4);
        s[tt] = (qa.x * ka.x + qa.y * ka.y + qa.z * ka.z + qa.w * ka.w +
                 qc.x * kc.x + qc.y * kc.y + qc.z * kc.z + qc.w * kc.w) * QSCALE;
    }
    float mx = s[0];
#pragma unroll
    for (int tt = 1; tt < SS; ++tt) mx = fmaxf(mx, s[tt]);
    float l = 0.f;
#pragma unroll
    for (int tt = 0; tt < SS; ++tt) { s[tt] = exp2f(s[tt] - mx); l += s[tt]; }
    float a0 = 0.f, a1 = 0.f, a2 = 0.f, a3 = 0.f, a4 = 0.f, a5 = 0.f, a6 = 0.f, a7 = 0.f;
#pragma unroll
    for (int tt = 0; tt < SS; ++tt) {
        const float* vp = vbase + tt * (NNODE * HIDN);
        float4 va = *(const float4*)vp;
        float4 vc = *(const float4*)(vp + 4);
        float e = s[tt];
        a0 += e * va.x; a1 += e * va.y; a2 += e * va.z; a3 += e * va.w;
        a4 += e * vc.x; a5 += e * vc.y; a6 += e * vc.z; a7 += e * vc.w;
    }
    float inv = 1.f / l;
    float* op = h + (rest * NNODE + n) * HIDN + hd * DHEAD;
    *(float4*)op       = make_float4(a0 * inv, a1 * inv, a2 * inv, a3 * inv);
    *(float4*)(op + 4) = make_float4(a4 * inv, a5 * inv, a6 * inv, a7 * inv);
}

// ---------------- output projection: h[:, S-1] @ raw WoutT + raw bout --------
__global__ void out_proj_kernel(const float* __restrict__ h, const void* __restrict__ W,
                                const void* __restrict__ b, void* __restrict__ out,
                                const int* __restrict__ flagp) {
    int fl = (*flagp != 0);
    int t = blockIdx.x * blockDim.x + threadIdx.x;
    if (t >= BB * NNODE * 3) return;
    int c  = t % 3;
    int bn = t / 3;
    int n  = bn & (NNODE - 1);
    int bb = bn >> 9;
    const float* hp = h + ((bb * SS + (SS - 1)) * NNODE + n) * HIDN;
    float a = ld(b, c, fl);
#pragma unroll
    for (int i = 0; i < HIDN; i += 4) {
        float4 h4 = *(const float4*)(hp + i);
        a += h4.x * ld(W, c * 64 + i,     fl) + h4.y * ld(W, c * 64 + i + 1, fl)
           + h4.z * ld(W, c * 64 + i + 2, fl) + h4.w * ld(W, c * 64 + i + 3, fl);
    }
    if (fl) ((float*)out)[t] = a;
    else    ((__hip_bfloat16*)out)[t] = __float2bfloat16(a);
}

extern "C" void kernel_launch(void* const* d_in, const int* in_sizes, int n_in,
                              void* d_out, int out_size, void* d_ws, size_t ws_size,
                              hipStream_t stream) {
    const int* ei = (const int*)d_in[1];

    float* ws = (float*)d_ws;
    int*   flag  = (int*)ws;               // 64 floats reserved
    u32*   maskT = (u32*)(ws + 64);        // 8192 u32
    float* wTs   = ws + 64 + 8192;         // 2*12288
    float* wTt   = wTs + 24576;            // 2*12288
    float* bsp   = wTt + 24576;            // 2*192
    float* btp   = bsp + 384;              // 2*192
    float* hbuf  = btp + 384;              // ROWS*64 each
    float* qbuf  = hbuf + ROWS * HIDN;
    float* kbuf  = qbuf + ROWS * HIDN;
    float* vbuf  = kbuf + ROWS * HIDN;
    u16*   qb16  = (u16*)qbuf;             // alias: spatial q bf16 (prescaled)
    u16*   kb16  = (u16*)kbuf;             // alias: spatial K bf16
    u16*   vb16  = (u16*)vbuf;             // alias: spatial V bf16

    // dtype from host-visible byte sizes; runtime-detect only if ambiguous
    int flv = -1;
    if (in_sizes) {
        if (in_sizes[0] == XELEMS * 2) flv = 0;        // bf16
        else if (in_sizes[0] == XELEMS * 4) flv = 1;   // fp32
    }
    if (flv >= 0) {
        (void)hipMemsetAsync(flag, flv, sizeof(int), stream);
    } else {
        (void)hipMemsetAsync(flag, 0, sizeof(int), stream);
        detect_kernel<<<64, 256, 0, stream>>>((const u16*)d_in[0], flag);
    }
    (void)hipMemsetAsync(maskT, 0, 8192 * sizeof(u32), stream);
    scatter_mask_kernel<<<NEDGE / 256, 256, 0, stream>>>(ei, maskT);

    PackArgs pa;
    pa.Wq[0] = d_in[4];  pa.bq[0] = d_in[5];
    pa.Wk[0] = d_in[6];  pa.bk[0] = d_in[7];
    pa.Wv[0] = d_in[8];  pa.bv[0] = d_in[9];
    pa.Wq[1] = d_in[10]; pa.bq[1] = d_in[11];
    pa.Wk[1] = d_in[12]; pa.bk[1] = d_in[13];
    pa.Wv[1] = d_in[14]; pa.bv[1] = d_in[15];
    pa.wT[0] = wTs; pa.bp[0] = bsp;
    pa.wT[1] = wTt; pa.bp[1] = btp;
    pack_kernel<<<dim3(48, NLAY, 2), 256, 0, stream>>>(pa, flag);

    input_proj_kernel<<<ROWS * HIDN / 256, 256, 0, stream>>>(
        d_in[0], d_in[2], d_in[3], hbuf, flag);

    const int GEMM_BLOCKS = ROWS / 32;                       // 768
    const int ATTN_BLOCKS = BB * SS * NHEADS * NNODE / 256;  // 768 (temporal)
    for (int l = 0; l < NLAY; ++l) {
        // spatial
        qkv_gemm_kernel<<<GEMM_BLOCKS, 256, 0, stream>>>(
            hbuf, wTs + l * 12288, bsp + l * 192, qbuf, kbuf, vbuf,
            qb16, kb16, vb16, 1);
        spatial_attn_kernel<<<BB * SS * NHEADS * 2, 256, 0, stream>>>(
            qb16, kb16, vb16, maskT, hbuf);
        // temporal
        qkv_gemm_kernel<<<GEMM_BLOCKS, 256, 0, stream>>>(
            hbuf, wTt + l * 12288, btp + l * 192, qbuf, kbuf, vbuf,
            qb16, kb16, vb16, 0);
        temporal_attn_kernel<<<ATTN_BLOCKS, 256, 0, stream>>>(qbuf, kbuf, vbuf, hbuf);
    }
    out_proj_kernel<<<(BB * NNODE * 3 + 255) / 256, 256, 0, stream>>>(
        hbuf, d_in[16], d_in[17], d_out, flag);
}

// Round 3
// 313.232 us; speedup vs baseline: 1.0417x; 1.0158x over previous
//
#include <hip/hip_runtime.h>
#include <hip/hip_bf16.h>

#define HIDN   64
#define NHEADS 8
#define DHEAD  8
#define NLAY   2
#define BB     4
#define SS     12
#define NNODE  512
#define NEDGE  8192
#define XELEMS (BB * SS * NNODE * 3)      // 73728
#define ROWS   (BB * SS * NNODE)          // 24576
#define QSCALE 0.51006967f                // (1/sqrt(8)) * log2(e): exp(x)=exp2(x*log2e)

typedef unsigned short u16;
typedef unsigned int   u32;

__device__ __forceinline__ float b2f(u16 u) {
    union { u32 i; float f; } c; c.i = ((u32)u) << 16; return c.f;
}
// decode element i of a raw input tensor (fl=1 -> fp32, fl=0 -> bf16)
__device__ __forceinline__ float ld(const void* p, int i, int fl) {
    return fl ? ((const float*)p)[i] : b2f(((const u16*)p)[i]);
}

// -------- dtype detection FALLBACK (only if in_sizes is ambiguous) -----------
__global__ void detect_kernel(const u16* __restrict__ x, int* __restrict__ flag) {
    int i0 = blockIdx.x * 256 + threadIdx.x;
    int bad = 0;
    for (int i = i0; i < XELEMS; i += 64 * 256) {
        float v = fabsf(b2f(x[i]));
        if (!(v <= 100.f)) bad = 1;   // catches huge AND NaN
    }
    if (bad) atomicOr(flag, 1);       // flag=1 -> inputs are fp32
}

// ---------------- pack W[l][j][i] (RAW input, decoded) -> wT[l][i][192], bias[l][192]
struct PackArgs {
    const void* Wq[2]; const void* bq[2];
    const void* Wk[2]; const void* bk[2];
    const void* Wv[2]; const void* bv[2];
    float* wT[2]; float* bp[2];
};
__global__ void pack_kernel(PackArgs a, const int* __restrict__ flagp) {
    int fl = (*flagp != 0);
    int p = blockIdx.z;
    int l = blockIdx.y;
    int t = blockIdx.x * 256 + threadIdx.x;   // 0..12287
    int i = t / 192, j = t - i * 192;
    int c = j >> 6, cc = j & 63;
    const void* W = (c == 0) ? a.Wq[p] : (c == 1) ? a.Wk[p] : a.Wv[p];
    a.wT[p][l * 12288 + t] = ld(W, l * 4096 + cc * 64 + i, fl);
    if (i == 0) {
        const void* B = (c == 0) ? a.bq[p] : (c == 1) ? a.bk[p] : a.bv[p];
        a.bp[p][l * 192 + j] = ld(B, l * 64 + cc, fl);
    }
}

// ---------------- edge mask, transposed bitmask: maskT[n][m>>5] bit (m&31) ---
__global__ void scatter_mask_kernel(const int* __restrict__ ei, u32* __restrict__ maskT) {
    int e = blockIdx.x * blockDim.x + threadIdx.x;
    if (e < NEDGE) {
        int n = ei[e];          // query row
        int m = ei[NEDGE + e];  // key col
        atomicOr(&maskT[n * 16 + (m >> 5)], 1u << (m & 31));
    }
}

// ---------------- CSR build from dedup'd bitmask: one block, 512 threads -----
// row_ptr[513]; col_idx[nnz] (u16). Hillis-Steele inclusive scan in LDS.
__global__ __launch_bounds__(512) void csr_kernel(const u32* __restrict__ maskT,
                                                  int* __restrict__ row_ptr,
                                                  u16* __restrict__ col_idx) {
    __shared__ int sc[512];
    int n = threadIdx.x;
    u32 w[16];
    int d = 0;
#pragma unroll
    for (int i = 0; i < 16; ++i) { w[i] = maskT[n * 16 + i]; d += __popc(w[i]); }
    sc[n] = d;
    __syncthreads();
    for (int s = 1; s < 512; s <<= 1) {
        int v = (n >= s) ? sc[n - s] : 0;
        __syncthreads();
        sc[n] += v;
        __syncthreads();
    }
    int excl = sc[n] - d;
    row_ptr[n] = excl;
    if (n == 511) row_ptr[512] = sc[511];
    int base = excl;
#pragma unroll
    for (int i = 0; i < 16; ++i) {
        u32 m = w[i];
        while (m) {
            int b = __ffs(m) - 1;
            m &= m - 1;
            col_idx[base++] = (u16)(i * 32 + b);
        }
    }
}

// ---------------- input projection: raw x [B,S,N,3] @ raw WinT + b -> h [ROWS,64]
__global__ void input_proj_kernel(const void* __restrict__ x, const void* __restrict__ W,
                                  const void* __restrict__ b, float* __restrict__ h,
                                  const int* __restrict__ flagp) {
    int fl = (*flagp != 0);
    int t = blockIdx.x * blockDim.x + threadIdx.x;  // row*64 + j
    int row = t >> 6, j = t & 63;
    float x0 = ld(x, row * 3, fl);
    float x1 = ld(x, row * 3 + 1, fl);
    float x2 = ld(x, row * 3 + 2, fl);
    h[t] = ld(b, j, fl) + x0 * ld(W, j * 3, fl) + x1 * ld(W, j * 3 + 1, fl)
                        + x2 * ld(W, j * 3 + 2, fl);
}

// ---------------- fused q/k/v GEMM (fp32 VALU, high-TLP) ---------------------
// block: 32 rows x 192 cols, 256 threads, 2x12 acc/thread, grid 768 = 3 blk/CU.
// spatial_layout=1: fp32 HEAD-MAJOR [bs*8+hd][n][8]; q prescaled by QSCALE.
// spatial_layout=0: fp32 row-major [row][64] (for temporal).
__global__ __launch_bounds__(256) void qkv_gemm_kernel(
    const float* __restrict__ h, const float* __restrict__ wT,
    const float* __restrict__ bias,
    float* __restrict__ q, float* __restrict__ k, float* __restrict__ v,
    int spatial_layout) {
    __shared__ float hT[64][36];    // [i][r], 32 rows + pad
    __shared__ float wS[32][192];   // [i-half][j]
    __shared__ float bS[192];
    int t = threadIdx.x;
    int row0 = blockIdx.x * 32;
    {
        int r = t & 31, ic = t >> 5;        // ic 0..7 -> i0 = ic*8
        const float* hp = h + (row0 + r) * 64 + ic * 8;
        float4 h0 = *(const float4*)hp;
        float4 h1 = *(const float4*)(hp + 4);
        int i = ic * 8;
        hT[i+0][r] = h0.x; hT[i+1][r] = h0.y; hT[i+2][r] = h0.z; hT[i+3][r] = h0.w;
        hT[i+4][r] = h1.x; hT[i+5][r] = h1.y; hT[i+6][r] = h1.z; hT[i+7][r] = h1.w;
    }
    {
        const float4* src = (const float4*)wT;
        float4* dst = (float4*)&wS[0][0];
#pragma unroll
        for (int c = 0; c < 6; ++c) dst[t + 256 * c] = src[t + 256 * c];
        if (t < 192) bS[t] = bias[t];
    }
    __syncthreads();
    int tc = t & 15, tr = t >> 4;
    int r0 = tc * 2, j0 = tr * 12;
    float acc[12][2];
#pragma unroll
    for (int j = 0; j < 12; ++j) {
        float bb = bS[j0 + j];
        acc[j][0] = bb; acc[j][1] = bb;
    }
#pragma unroll 4
    for (int i = 0; i < 32; ++i) {
        float2 a = *(const float2*)&hT[i][r0];
#pragma unroll
        for (int jj = 0; jj < 3; ++jj) {
            float4 w = *(const float4*)&wS[i][j0 + jj * 4];
            int jb = jj * 4;
            acc[jb+0][0] += w.x*a.x; acc[jb+0][1] += w.x*a.y;
            acc[jb+1][0] += w.y*a.x; acc[jb+1][1] += w.y*a.y;
            acc[jb+2][0] += w.z*a.x; acc[jb+2][1] += w.z*a.y;
            acc[jb+3][0] += w.w*a.x; acc[jb+3][1] += w.w*a.y;
        }
    }
    __syncthreads();
    {
        const float4* src = (const float4*)(wT + 32 * 192);
        float4* dst = (float4*)&wS[0][0];
#pragma unroll
        for (int c = 0; c < 6; ++c) dst[t + 256 * c] = src[t + 256 * c];
    }
    __syncthreads();
#pragma unroll 4
    for (int i = 0; i < 32; ++i) {
        float2 a = *(const float2*)&hT[32 + i][r0];
#pragma unroll
        for (int jj = 0; jj < 3; ++jj) {
            float4 w = *(const float4*)&wS[i][j0 + jj * 4];
            int jb = jj * 4;
            acc[jb+0][0] += w.x*a.x; acc[jb+0][1] += w.x*a.y;
            acc[jb+1][0] += w.y*a.x; acc[jb+1][1] += w.y*a.y;
            acc[jb+2][0] += w.z*a.x; acc[jb+2][1] += w.z*a.y;
            acc[jb+3][0] += w.w*a.x; acc[jb+3][1] += w.w*a.y;
        }
    }
#pragma unroll
    for (int j = 0; j < 12; ++j) {
        int jj = j0 + j;
        int cc = jj & 63;
#pragma unroll
        for (int r = 0; r < 2; ++r) {
            int row = row0 + r0 + r;
            float val = acc[j][r];
            if (spatial_layout) {
                int bs = row >> 9, n = row & 511;
                int idx = ((bs * 8 + (cc >> 3)) * 512 + n) * 8 + (cc & 7);
                if (jj < 64)       q[idx] = val * QSCALE;
                else if (jj < 128) k[idx] = val;
                else               v[idx] = val;
            } else {
                int idx = row * 64 + cc;
                float* dst = (jj < 64) ? q : (jj < 128) ? k : v;
                dst[idx] = val;
            }
        }
    }
}

// ---------------- spatial attention v10: SPARSE (avg degree 16/512) ----------
// grid 768 = (pair=bs*8+hd [384]) x (rowhalf [2]); 256 threads, 1 thread = 1 query row.
// K,V fp32 head-major staged in LDS (32 KB). Per row: loop CSR neighbors:
// 8-dot (q prescaled by QSCALE), exp2, 8-AXPY. deg==0 -> uniform mean(V).
// Exact vs reference: masked entries underflow to exactly 0 in fp32 softmax.
__global__ __launch_bounds__(256) void spatial_attn_kernel(
    const float* __restrict__ qh, const float* __restrict__ kh, const float* __restrict__ vh,
    const int* __restrict__ row_ptr, const u16* __restrict__ col_idx,
    float* __restrict__ h) {
    __shared__ __align__(16) float Ks[NNODE][8];   // 16 KB
    __shared__ __align__(16) float Vs[NNODE][8];   // 16 KB
    int bxx = blockIdx.x;
    int pair = bxx >> 1, halfq = bxx & 1;
    int bs = pair >> 3, hd = pair & 7;      // bs = b*S+s in [0,48)
    const float* kp = kh + pair * (NNODE * 8);
    const float* vp = vh + pair * (NNODE * 8);
    int t = threadIdx.x;
#pragma unroll
    for (int i = 0; i < 2; ++i) {
        int r = t + 256 * i;
        float4 k0 = *(const float4*)(kp + r * 8);
        float4 k1 = *(const float4*)(kp + r * 8 + 4);
        float4 v0 = *(const float4*)(vp + r * 8);
        float4 v1 = *(const float4*)(vp + r * 8 + 4);
        *(float4*)&Ks[r][0] = k0; *(float4*)&Ks[r][4] = k1;
        *(float4*)&Vs[r][0] = v0; *(float4*)&Vs[r][4] = v1;
    }
    __syncthreads();
    int n = halfq * 256 + t;
    const float* qp = qh + (pair * NNODE + n) * 8;
    float4 qa = *(const float4*)qp;
    float4 qc = *(const float4*)(qp + 4);
    int e0 = row_ptr[n], e1 = row_ptr[n + 1];
    float l = 0.f;
    float o0=0.f,o1=0.f,o2=0.f,o3=0.f,o4=0.f,o5=0.f,o6=0.f,o7=0.f;
    for (int e = e0; e < e1; ++e) {
        int m = col_idx[e];
        float4 ka = *(const float4*)&Ks[m][0];
        float4 kc = *(const float4*)&Ks[m][4];
        float s = qa.x*ka.x + qa.y*ka.y + qa.z*ka.z + qa.w*ka.w
                + qc.x*kc.x + qc.y*kc.y + qc.z*kc.z + qc.w*kc.w;
        float p = exp2f(s);          // q prescaled by (1/sqrt8)*log2e
        l += p;
        float4 va = *(const float4*)&Vs[m][0];
        float4 vc = *(const float4*)&Vs[m][4];
        o0 += p*va.x; o1 += p*va.y; o2 += p*va.z; o3 += p*va.w;
        o4 += p*vc.x; o5 += p*vc.y; o6 += p*vc.z; o7 += p*vc.w;
    }
    if (e1 == e0) {                  // fully-masked row: uniform mean(V)
        for (int m = 0; m < NNODE; ++m) {
            o0 += Vs[m][0]; o1 += Vs[m][1]; o2 += Vs[m][2]; o3 += Vs[m][3];
            o4 += Vs[m][4]; o5 += Vs[m][5]; o6 += Vs[m][6]; o7 += Vs[m][7];
        }
        l = (float)NNODE;
    }
    float inv = 1.f / l;
    float* op = h + (bs * NNODE + n) * HIDN + hd * 8;
    *(float4*)op       = make_float4(o0*inv, o1*inv, o2*inv, o3*inv);
    *(float4*)(op + 4) = make_float4(o4*inv, o5*inv, o6*inv, o7*inv);
}

// ---------------- temporal attention: thread per (b,s,n,h), loop t (S=12) ----
__global__ __launch_bounds__(256) void temporal_attn_kernel(
    const float* __restrict__ q, const float* __restrict__ k, const float* __restrict__ v,
    float* __restrict__ h) {
    int t    = blockIdx.x * blockDim.x + threadIdx.x;
    int hd   = t & 7;
    int n    = (t >> 3) & (NNODE - 1);
    int rest = t >> 12;  // b*S + sq
    int b    = rest / SS;
    const float* qp = q + (rest * NNODE + n) * HIDN + hd * DHEAD;
    float4 qa = *(const float4*)qp;
    float4 qc = *(const float4*)(qp + 4);
    const float* kbase = k + (b * SS * NNODE + n) * HIDN + hd * DHEAD;
    const float* vbase = v + (b * SS * NNODE + n) * HIDN + hd * DHEAD;
    float s[SS];
#pragma unroll
    for (int tt = 0; tt < SS; ++tt) {
        const float* kp = kbase + tt * (NNODE * HIDN);
        float4 ka = *(const float4*)kp;
        float4 kc = *(const float4*)(kp + 4);
        s[tt] = (qa.x * ka.x + qa.y * ka.y + qa.z * ka.z + qa.w * ka.w +
                 qc.x * kc.x + qc.y * kc.y + qc.z * kc.z + qc.w * kc.w) * QSCALE;
    }
    float mx = s[0];
#pragma unroll
    for (int tt = 1; tt < SS; ++tt) mx = fmaxf(mx, s[tt]);
    float l = 0.f;
#pragma unroll
    for (int tt = 0; tt < SS; ++tt) { s[tt] = exp2f(s[tt] - mx); l += s[tt]; }
    float a0 = 0.f, a1 = 0.f, a2 = 0.f, a3 = 0.f, a4 = 0.f, a5 = 0.f, a6 = 0.f, a7 = 0.f;
#pragma unroll
    for (int tt = 0; tt < SS; ++tt) {
        const float* vp = vbase + tt * (NNODE * HIDN);
        float4 va = *(const float4*)vp;
        float4 vc = *(const float4*)(vp + 4);
        float e = s[tt];
        a0 += e * va.x; a1 += e * va.y; a2 += e * va.z; a3 += e * va.w;
        a4 += e * vc.x; a5 += e * vc.y; a6 += e * vc.z; a7 += e * vc.w;
    }
    float inv = 1.f / l;
    float* op = h + (rest * NNODE + n) * HIDN + hd * DHEAD;
    *(float4*)op       = make_float4(a0 * inv, a1 * inv, a2 * inv, a3 * inv);
    *(float4*)(op + 4) = make_float4(a4 * inv, a5 * inv, a6 * inv, a7 * inv);
}

// ---------------- output projection: h[:, S-1] @ raw WoutT + raw bout --------
__global__ void out_proj_kernel(const float* __restrict__ h, const void* __restrict__ W,
                                const void* __restrict__ b, void* __restrict__ out,
                                const int* __restrict__ flagp) {
    int fl = (*flagp != 0);
    int t = blockIdx.x * blockDim.x + threadIdx.x;
    if (t >= BB * NNODE * 3) return;
    int c  = t % 3;
    int bn = t / 3;
    int n  = bn & (NNODE - 1);
    int bb = bn >> 9;
    const float* hp = h + ((bb * SS + (SS - 1)) * NNODE + n) * HIDN;
    float a = ld(b, c, fl);
#pragma unroll
    for (int i = 0; i < HIDN; i += 4) {
        float4 h4 = *(const float4*)(hp + i);
        a += h4.x * ld(W, c * 64 + i,     fl) + h4.y * ld(W, c * 64 + i + 1, fl)
           + h4.z * ld(W, c * 64 + i + 2, fl) + h4.w * ld(W, c * 64 + i + 3, fl);
    }
    if (fl) ((float*)out)[t] = a;
    else    ((__hip_bfloat16*)out)[t] = __float2bfloat16(a);
}

extern "C" void kernel_launch(void* const* d_in, const int* in_sizes, int n_in,
                              void* d_out, int out_size, void* d_ws, size_t ws_size,
                              hipStream_t stream) {
    const int* ei = (const int*)d_in[1];

    float* ws = (float*)d_ws;
    int*   flag    = (int*)ws;                   // 64 floats reserved
    u32*   maskT   = (u32*)(ws + 64);            // 8192 u32
    int*   row_ptr = (int*)(ws + 64 + 8192);     // 513 ints (reserve 640)
    u16*   col_idx = (u16*)(ws + 64 + 8192 + 640); // 8192 u16 (4096 float slots)
    float* wTs   = ws + 64 + 8192 + 640 + 4096;  // 2*12288
    float* wTt   = wTs + 24576;                  // 2*12288
    float* bsp   = wTt + 24576;                  // 2*192
    float* btp   = bsp + 384;                    // 2*192
    float* hbuf  = btp + 384;                    // ROWS*64 each
    float* qbuf  = hbuf + ROWS * HIDN;
    float* kbuf  = qbuf + ROWS * HIDN;
    float* vbuf  = kbuf + ROWS * HIDN;

    // dtype from host-visible byte sizes; runtime-detect only if ambiguous
    int flv = -1;
    if (in_sizes) {
        if (in_sizes[0] == XELEMS * 2) flv = 0;        // bf16
        else if (in_sizes[0] == XELEMS * 4) flv = 1;   // fp32
    }
    if (flv >= 0) {
        (void)hipMemsetAsync(flag, flv, sizeof(int), stream);
    } else {
        (void)hipMemsetAsync(flag, 0, sizeof(int), stream);
        detect_kernel<<<64, 256, 0, stream>>>((const u16*)d_in[0], flag);
    }
    (void)hipMemsetAsync(maskT, 0, 8192 * sizeof(u32), stream);
    scatter_mask_kernel<<<NEDGE / 256, 256, 0, stream>>>(ei, maskT);
    csr_kernel<<<1, 512, 0, stream>>>(maskT, row_ptr, col_idx);

    PackArgs pa;
    pa.Wq[0] = d_in[4];  pa.bq[0] = d_in[5];
    pa.Wk[0] = d_in[6];  pa.bk[0] = d_in[7];
    pa.Wv[0] = d_in[8];  pa.bv[0] = d_in[9];
    pa.Wq[1] = d_in[10]; pa.bq[1] = d_in[11];
    pa.Wk[1] = d_in[12]; pa.bk[1] = d_in[13];
    pa.Wv[1] = d_in[14]; pa.bv[1] = d_in[15];
    pa.wT[0] = wTs; pa.bp[0] = bsp;
    pa.wT[1] = wTt; pa.bp[1] = btp;
    pack_kernel<<<dim3(48, NLAY, 2), 256, 0, stream>>>(pa, flag);

    input_proj_kernel<<<ROWS * HIDN / 256, 256, 0, stream>>>(
        d_in[0], d_in[2], d_in[3], hbuf, flag);

    const int GEMM_BLOCKS = ROWS / 32;                       // 768
    const int ATTN_BLOCKS = BB * SS * NHEADS * NNODE / 256;  // 768 (temporal)
    for (int l = 0; l < NLAY; ++l) {
        // spatial
        qkv_gemm_kernel<<<GEMM_BLOCKS, 256, 0, stream>>>(
            hbuf, wTs + l * 12288, bsp + l * 192, qbuf, kbuf, vbuf, 1);
        spatial_attn_kernel<<<BB * SS * NHEADS * 2, 256, 0, stream>>>(
            qbuf, kbuf, vbuf, row_ptr, col_idx, hbuf);
        // temporal
        qkv_gemm_kernel<<<GEMM_BLOCKS, 256, 0, stream>>>(
            hbuf, wTt + l * 12288, btp + l * 192, qbuf, kbuf, vbuf, 0);
        temporal_attn_kernel<<<ATTN_BLOCKS, 256, 0, stream>>>(qbuf, kbuf, vbuf, hbuf);
    }
    out_proj_kernel<<<(BB * NNODE * 3 + 255) / 256, 256, 0, stream>>>(
        hbuf, d_in[16], d_in[17], d_out, flag);
}

// Round 4
// 242.854 us; speedup vs baseline: 1.3436x; 1.2898x over previous
//
#include <hip/hip_runtime.h>
#include <hip/hip_bf16.h>

#define HIDN   64
#define NHEADS 8
#define DHEAD  8
#define NLAY   2
#define BB     4
#define SS     12
#define NNODE  512
#define NEDGE  8192
#define XELEMS (BB * SS * NNODE * 3)      // 73728
#define ROWS   (BB * SS * NNODE)          // 24576
#define QSCALE 0.51006967f                // (1/sqrt(8)) * log2(e): exp(x)=exp2(x*log2e)

typedef unsigned short u16;
typedef unsigned int   u32;
typedef __attribute__((ext_vector_type(4))) float f4;   // indexable float4

__device__ __forceinline__ float b2f(u16 u) {
    union { u32 i; float f; } c; c.i = ((u32)u) << 16; return c.f;
}
// decode element i of a raw input tensor (fl=1 -> fp32, fl=0 -> bf16)
__device__ __forceinline__ float ld(const void* p, int i, int fl) {
    return fl ? ((const float*)p)[i] : b2f(((const u16*)p)[i]);
}

// -------- dtype detection FALLBACK (only if in_sizes is ambiguous) -----------
__global__ void detect_kernel(const u16* __restrict__ x, int* __restrict__ flag) {
    int i0 = blockIdx.x * 256 + threadIdx.x;
    int bad = 0;
    for (int i = i0; i < XELEMS; i += 64 * 256) {
        float v = fabsf(b2f(x[i]));
        if (!(v <= 100.f)) bad = 1;   // catches huge AND NaN
    }
    if (bad) atomicOr(flag, 1);       // flag=1 -> inputs are fp32
}

// ---------------- pack W (RAW input, decoded) -> wT[l][phase][j][iloc] -------
// layout: linear t = phase*6144 + j*32 + iloc, i = phase*32 + iloc; j in [0,192).
// This makes the qkv GEMM's LDS staging a pure linear float4 copy.
struct PackArgs {
    const void* Wq[2]; const void* bq[2];
    const void* Wk[2]; const void* bk[2];
    const void* Wv[2]; const void* bv[2];
    float* wT[2]; float* bp[2];
};
__global__ void pack_kernel(PackArgs a, const int* __restrict__ flagp) {
    int fl = (*flagp != 0);
    int p = blockIdx.z;
    int l = blockIdx.y;
    int t = blockIdx.x * 256 + threadIdx.x;   // 0..12287
    int ph   = (t >= 6144) ? 1 : 0;
    int rem  = t - ph * 6144;
    int j    = rem >> 5;
    int iloc = rem & 31;
    int i    = ph * 32 + iloc;
    int c = j >> 6, cc = j & 63;
    const void* W = (c == 0) ? a.Wq[p] : (c == 1) ? a.Wk[p] : a.Wv[p];
    a.wT[p][l * 12288 + t] = ld(W, l * 4096 + cc * 64 + i, fl);
    if (ph == 0 && iloc == 0) {
        const void* B = (c == 0) ? a.bq[p] : (c == 1) ? a.bk[p] : a.bv[p];
        a.bp[p][l * 192 + j] = ld(B, l * 64 + cc, fl);
    }
}

// ---------------- edge mask, transposed bitmask: maskT[n][m>>5] bit (m&31) ---
__global__ void scatter_mask_kernel(const int* __restrict__ ei, u32* __restrict__ maskT) {
    int e = blockIdx.x * blockDim.x + threadIdx.x;
    if (e < NEDGE) {
        int n = ei[e];          // query row
        int m = ei[NEDGE + e];  // key col
        atomicOr(&maskT[n * 16 + (m >> 5)], 1u << (m & 31));
    }
}

// ---------------- CSR build from dedup'd bitmask: one block, 512 threads -----
__global__ __launch_bounds__(512) void csr_kernel(const u32* __restrict__ maskT,
                                                  int* __restrict__ row_ptr,
                                                  u16* __restrict__ col_idx) {
    __shared__ int sc[512];
    int n = threadIdx.x;
    u32 w[16];
    int d = 0;
#pragma unroll
    for (int i = 0; i < 16; ++i) { w[i] = maskT[n * 16 + i]; d += __popc(w[i]); }
    sc[n] = d;
    __syncthreads();
    for (int s = 1; s < 512; s <<= 1) {
        int v = (n >= s) ? sc[n - s] : 0;
        __syncthreads();
        sc[n] += v;
        __syncthreads();
    }
    int excl = sc[n] - d;
    row_ptr[n] = excl;
    if (n == 511) row_ptr[512] = sc[511];
    int base = excl;
#pragma unroll
    for (int i = 0; i < 16; ++i) {
        u32 m = w[i];
        while (m) {
            int b = __ffs(m) - 1;
            m &= m - 1;
            col_idx[base++] = (u16)(i * 32 + b);
        }
    }
}

// ---------------- input projection: raw x [B,S,N,3] @ raw WinT + b -> h [ROWS,64]
__global__ void input_proj_kernel(const void* __restrict__ x, const void* __restrict__ W,
                                  const void* __restrict__ b, float* __restrict__ h,
                                  const int* __restrict__ flagp) {
    int fl = (*flagp != 0);
    int t = blockIdx.x * blockDim.x + threadIdx.x;  // row*64 + j
    int row = t >> 6, j = t & 63;
    float x0 = ld(x, row * 3, fl);
    float x1 = ld(x, row * 3 + 1, fl);
    float x2 = ld(x, row * 3 + 2, fl);
    h[t] = ld(b, j, fl) + x0 * ld(W, j * 3, fl) + x1 * ld(W, j * 3 + 1, fl)
                        + x2 * ld(W, j * 3 + 2, fl);
}

// ---------------- fused q/k/v GEMM v2: coalesced everywhere ------------------
// block: 32 rows x 192 cols, 256 threads. thread = (wave w = row octet, lane c = col).
// acc[3][8]: tensor g (q/k/v), 8 rows. All global loads/stores lane-consecutive.
// Inner loop: per 4 i: 8 wave-uniform b128 (hS broadcast) + 3 b128 (wST), 96 FMA.
// Accumulation order over i identical to v1 -> bit-identical outputs.
__global__ __launch_bounds__(256) void qkv_gemm_kernel(
    const float* __restrict__ h, const float* __restrict__ wT,
    const float* __restrict__ bias,
    float* __restrict__ q, float* __restrict__ k, float* __restrict__ v,
    int spatial_layout) {
    __shared__ float hS[32][68];    // [row][i 0..63], pad 68
    __shared__ float wST[192][36];  // per-phase [col j][iloc 0..31], pad 36
    __shared__ float bS[192];
    int t = threadIdx.x;
    int row0 = blockIdx.x * 32;
    // stage hS: fully coalesced float4 loads + 2-way-free LDS writes
    {
        const float4* src = (const float4*)(h + row0 * 64);
        float4 a0 = src[t];
        float4 a1 = src[t + 256];
        int rs = t >> 4, cs = (t & 15) * 4;
        *(float4*)&hS[rs][cs]      = a0;
        *(float4*)&hS[16 + rs][cs] = a1;
    }
    // stage wST phase 0 (linear copy thanks to pack layout) + bias
    {
        const float4* src = (const float4*)wT;
#pragma unroll
        for (int kk = 0; kk < 6; ++kk) {
            float4 w4 = src[t + 256 * kk];
            int idx = 4 * (t + 256 * kk);    // = j*32 + iloc
            int j = idx >> 5, il = idx & 31;
            *(float4*)&wST[j][il] = w4;
        }
        if (t < 192) bS[t] = bias[t];
    }
    __syncthreads();
    int c = t & 63, w = t >> 6;
    int rbase = w * 8;
    float acc[3][8];
#pragma unroll
    for (int g = 0; g < 3; ++g) {
        float bb = bS[g * 64 + c];
#pragma unroll
        for (int rr = 0; rr < 8; ++rr) acc[g][rr] = bb;
    }
    // ---- phase 0: i = 0..31
#pragma unroll 2
    for (int i0 = 0; i0 < 32; i0 += 4) {
        f4 hv[8];
#pragma unroll
        for (int rr = 0; rr < 8; ++rr) hv[rr] = *(const f4*)&hS[rbase + rr][i0];
        f4 wv[3];
        wv[0] = *(const f4*)&wST[c][i0];
        wv[1] = *(const f4*)&wST[64 + c][i0];
        wv[2] = *(const f4*)&wST[128 + c][i0];
#pragma unroll
        for (int ii = 0; ii < 4; ++ii)
#pragma unroll
            for (int g = 0; g < 3; ++g) {
                float wf = wv[g][ii];
#pragma unroll
                for (int rr = 0; rr < 8; ++rr) acc[g][rr] += hv[rr][ii] * wf;
            }
    }
    __syncthreads();
    // stage wST phase 1
    {
        const float4* src = (const float4*)(wT + 6144);
#pragma unroll
        for (int kk = 0; kk < 6; ++kk) {
            float4 w4 = src[t + 256 * kk];
            int idx = 4 * (t + 256 * kk);
            int j = idx >> 5, il = idx & 31;
            *(float4*)&wST[j][il] = w4;
        }
    }
    __syncthreads();
    // ---- phase 1: i = 32..63
#pragma unroll 2
    for (int i0 = 0; i0 < 32; i0 += 4) {
        f4 hv[8];
#pragma unroll
        for (int rr = 0; rr < 8; ++rr) hv[rr] = *(const f4*)&hS[rbase + rr][32 + i0];
        f4 wv[3];
        wv[0] = *(const f4*)&wST[c][i0];
        wv[1] = *(const f4*)&wST[64 + c][i0];
        wv[2] = *(const f4*)&wST[128 + c][i0];
#pragma unroll
        for (int ii = 0; ii < 4; ++ii)
#pragma unroll
            for (int g = 0; g < 3; ++g) {
                float wf = wv[g][ii];
#pragma unroll
                for (int rr = 0; rr < 8; ++rr) acc[g][rr] += hv[rr][ii] * wf;
            }
    }
    // ---- epilogue: lane-consecutive stores
    if (spatial_layout) {
        int bs = row0 >> 9, n0 = row0 & 511;
        int hd = c >> 3, dh = c & 7;
        long off = ((long)(bs * 8 + hd) * 512 + n0 + rbase) * 8 + dh;
        float* qp = q + off;
        float* kp = k + off;
        float* vp = v + off;
#pragma unroll
        for (int rr = 0; rr < 8; ++rr) {
            qp[rr * 8] = acc[0][rr] * QSCALE;
            kp[rr * 8] = acc[1][rr];
            vp[rr * 8] = acc[2][rr];
        }
    } else {
        int off = (row0 + rbase) * 64 + c;
        float* qp = q + off;
        float* kp = k + off;
        float* vp = v + off;
#pragma unroll
        for (int rr = 0; rr < 8; ++rr) {
            qp[rr * 64] = acc[0][rr];
            kp[rr * 64] = acc[1][rr];
            vp[rr * 64] = acc[2][rr];
        }
    }
}

// ---------------- spatial attention: SPARSE (avg degree 16/512) --------------
__global__ __launch_bounds__(256) void spatial_attn_kernel(
    const float* __restrict__ qh, const float* __restrict__ kh, const float* __restrict__ vh,
    const int* __restrict__ row_ptr, const u16* __restrict__ col_idx,
    float* __restrict__ h) {
    __shared__ __align__(16) float Ks[NNODE][8];   // 16 KB
    __shared__ __align__(16) float Vs[NNODE][8];   // 16 KB
    int bxx = blockIdx.x;
    int pair = bxx >> 1, halfq = bxx & 1;
    int bs = pair >> 3, hd = pair & 7;      // bs = b*S+s in [0,48)
    const float* kp = kh + pair * (NNODE * 8);
    const float* vp = vh + pair * (NNODE * 8);
    int t = threadIdx.x;
#pragma unroll
    for (int i = 0; i < 2; ++i) {
        int r = t + 256 * i;
        float4 k0 = *(const float4*)(kp + r * 8);
        float4 k1 = *(const float4*)(kp + r * 8 + 4);
        float4 v0 = *(const float4*)(vp + r * 8);
        float4 v1 = *(const float4*)(vp + r * 8 + 4);
        *(float4*)&Ks[r][0] = k0; *(float4*)&Ks[r][4] = k1;
        *(float4*)&Vs[r][0] = v0; *(float4*)&Vs[r][4] = v1;
    }
    __syncthreads();
    int n = halfq * 256 + t;
    const float* qp = qh + (pair * NNODE + n) * 8;
    float4 qa = *(const float4*)qp;
    float4 qc = *(const float4*)(qp + 4);
    int e0 = row_ptr[n], e1 = row_ptr[n + 1];
    float l = 0.f;
    float o0=0.f,o1=0.f,o2=0.f,o3=0.f,o4=0.f,o5=0.f,o6=0.f,o7=0.f;
    for (int e = e0; e < e1; ++e) {
        int m = col_idx[e];
        float4 ka = *(const float4*)&Ks[m][0];
        float4 kc = *(const float4*)&Ks[m][4];
        float s = qa.x*ka.x + qa.y*ka.y + qa.z*ka.z + qa.w*ka.w
                + qc.x*kc.x + qc.y*kc.y + qc.z*kc.z + qc.w*kc.w;
        float p = exp2f(s);          // q prescaled by (1/sqrt8)*log2e
        l += p;
        float4 va = *(const float4*)&Vs[m][0];
        float4 vc = *(const float4*)&Vs[m][4];
        o0 += p*va.x; o1 += p*va.y; o2 += p*va.z; o3 += p*va.w;
        o4 += p*vc.x; o5 += p*vc.y; o6 += p*vc.z; o7 += p*vc.w;
    }
    if (e1 == e0) {                  // fully-masked row: uniform mean(V)
        for (int m = 0; m < NNODE; ++m) {
            o0 += Vs[m][0]; o1 += Vs[m][1]; o2 += Vs[m][2]; o3 += Vs[m][3];
            o4 += Vs[m][4]; o5 += Vs[m][5]; o6 += Vs[m][6]; o7 += Vs[m][7];
        }
        l = (float)NNODE;
    }
    float inv = 1.f / l;
    float* op = h + (bs * NNODE + n) * HIDN + hd * 8;
    *(float4*)op       = make_float4(o0*inv, o1*inv, o2*inv, o3*inv);
    *(float4*)(op + 4) = make_float4(o4*inv, o5*inv, o6*inv, o7*inv);
}

// ---------------- temporal attention: thread per (b,s,n,h), loop t (S=12) ----
__global__ __launch_bounds__(256) void temporal_attn_kernel(
    const float* __restrict__ q, const float* __restrict__ k, const float* __restrict__ v,
    float* __restrict__ h) {
    int t    = blockIdx.x * blockDim.x + threadIdx.x;
    int hd   = t & 7;
    int n    = (t >> 3) & (NNODE - 1);
    int rest = t >> 12;  // b*S + sq
    int b    = rest / SS;
    const float* qp = q + (rest * NNODE + n) * HIDN + hd * DHEAD;
    float4 qa = *(const float4*)qp;
    float4 qc = *(const float4*)(qp + 4);
    const float* kbase = k + (b * SS * NNODE + n) * HIDN + hd * DHEAD;
    const float* vbase = v + (b * SS * NNODE + n) * HIDN + hd * DHEAD;
    float s[SS];
#pragma unroll
    for (int tt = 0; tt < SS; ++tt) {
        const float* kp = kbase + tt * (NNODE * HIDN);
        float4 ka = *(const float4*)kp;
        float4 kc = *(const float4*)(kp + 4);
        s[tt] = (qa.x * ka.x + qa.y * ka.y + qa.z * ka.z + qa.w * ka.w +
                 qc.x * kc.x + qc.y * kc.y + qc.z * kc.z + qc.w * kc.w) * QSCALE;
    }
    float mx = s[0];
#pragma unroll
    for (int tt = 1; tt < SS; ++tt) mx = fmaxf(mx, s[tt]);
    float l = 0.f;
#pragma unroll
    for (int tt = 0; tt < SS; ++tt) { s[tt] = exp2f(s[tt] - mx); l += s[tt]; }
    float a0 = 0.f, a1 = 0.f, a2 = 0.f, a3 = 0.f, a4 = 0.f, a5 = 0.f, a6 = 0.f, a7 = 0.f;
#pragma unroll
    for (int tt = 0; tt < SS; ++tt) {
        const float* vp = vbase + tt * (NNODE * HIDN);
        float4 va = *(const float4*)vp;
        float4 vc = *(const float4*)(vp + 4);
        float e = s[tt];
        a0 += e * va.x; a1 += e * va.y; a2 += e * va.z; a3 += e * va.w;
        a4 += e * vc.x; a5 += e * vc.y; a6 += e * vc.z; a7 += e * vc.w;
    }
    float inv = 1.f / l;
    float* op = h + (rest * NNODE + n) * HIDN + hd * DHEAD;
    *(float4*)op       = make_float4(a0 * inv, a1 * inv, a2 * inv, a3 * inv);
    *(float4*)(op + 4) = make_float4(a4 * inv, a5 * inv, a6 * inv, a7 * inv);
}

// ---------------- output projection: h[:, S-1] @ raw WoutT + raw bout --------
__global__ void out_proj_kernel(const float* __restrict__ h, const void* __restrict__ W,
                                const void* __restrict__ b, void* __restrict__ out,
                                const int* __restrict__ flagp) {
    int fl = (*flagp != 0);
    int t = blockIdx.x * blockDim.x + threadIdx.x;
    if (t >= BB * NNODE * 3) return;
    int c  = t % 3;
    int bn = t / 3;
    int n  = bn & (NNODE - 1);
    int bb = bn >> 9;
    const float* hp = h + ((bb * SS + (SS - 1)) * NNODE + n) * HIDN;
    float a = ld(b, c, fl);
#pragma unroll
    for (int i = 0; i < HIDN; i += 4) {
        float4 h4 = *(const float4*)(hp + i);
        a += h4.x * ld(W, c * 64 + i,     fl) + h4.y * ld(W, c * 64 + i + 1, fl)
           + h4.z * ld(W, c * 64 + i + 2, fl) + h4.w * ld(W, c * 64 + i + 3, fl);
    }
    if (fl) ((float*)out)[t] = a;
    else    ((__hip_bfloat16*)out)[t] = __float2bfloat16(a);
}

extern "C" void kernel_launch(void* const* d_in, const int* in_sizes, int n_in,
                              void* d_out, int out_size, void* d_ws, size_t ws_size,
                              hipStream_t stream) {
    const int* ei = (const int*)d_in[1];

    float* ws = (float*)d_ws;
    int*   flag    = (int*)ws;                   // 64 floats reserved
    u32*   maskT   = (u32*)(ws + 64);            // 8192 u32
    int*   row_ptr = (int*)(ws + 64 + 8192);     // 513 ints (reserve 640)
    u16*   col_idx = (u16*)(ws + 64 + 8192 + 640); // 8192 u16 (4096 float slots)
    float* wTs   = ws + 64 + 8192 + 640 + 4096;  // 2*12288
    float* wTt   = wTs + 24576;                  // 2*12288
    float* bsp   = wTt + 24576;                  // 2*192
    float* btp   = bsp + 384;                    // 2*192
    float* hbuf  = btp + 384;                    // ROWS*64 each
    float* qbuf  = hbuf + ROWS * HIDN;
    float* kbuf  = qbuf + ROWS * HIDN;
    float* vbuf  = kbuf + ROWS * HIDN;

    // dtype from host-visible byte sizes; runtime-detect only if ambiguous
    int flv = -1;
    if (in_sizes) {
        if (in_sizes[0] == XELEMS * 2) flv = 0;        // bf16
        else if (in_sizes[0] == XELEMS * 4) flv = 1;   // fp32
    }
    if (flv >= 0) {
        (void)hipMemsetAsync(flag, flv, sizeof(int), stream);
    } else {
        (void)hipMemsetAsync(flag, 0, sizeof(int), stream);
        detect_kernel<<<64, 256, 0, stream>>>((const u16*)d_in[0], flag);
    }
    (void)hipMemsetAsync(maskT, 0, 8192 * sizeof(u32), stream);
    scatter_mask_kernel<<<NEDGE / 256, 256, 0, stream>>>(ei, maskT);
    csr_kernel<<<1, 512, 0, stream>>>(maskT, row_ptr, col_idx);

    PackArgs pa;
    pa.Wq[0] = d_in[4];  pa.bq[0] = d_in[5];
    pa.Wk[0] = d_in[6];  pa.bk[0] = d_in[7];
    pa.Wv[0] = d_in[8];  pa.bv[0] = d_in[9];
    pa.Wq[1] = d_in[10]; pa.bq[1] = d_in[11];
    pa.Wk[1] = d_in[12]; pa.bk[1] = d_in[13];
    pa.Wv[1] = d_in[14]; pa.bv[1] = d_in[15];
    pa.wT[0] = wTs; pa.bp[0] = bsp;
    pa.wT[1] = wTt; pa.bp[1] = btp;
    pack_kernel<<<dim3(48, NLAY, 2), 256, 0, stream>>>(pa, flag);

    input_proj_kernel<<<ROWS * HIDN / 256, 256, 0, stream>>>(
        d_in[0], d_in[2], d_in[3], hbuf, flag);

    const int GEMM_BLOCKS = ROWS / 32;                       // 768
    const int ATTN_BLOCKS = BB * SS * NHEADS * NNODE / 256;  // 768 (temporal)
    for (int l = 0; l < NLAY; ++l) {
        // spatial
        qkv_gemm_kernel<<<GEMM_BLOCKS, 256, 0, stream>>>(
            hbuf, wTs + l * 12288, bsp + l * 192, qbuf, kbuf, vbuf, 1);
        spatial_attn_kernel<<<BB * SS * NHEADS * 2, 256, 0, stream>>>(
            qbuf, kbuf, vbuf, row_ptr, col_idx, hbuf);
        // temporal
        qkv_gemm_kernel<<<GEMM_BLOCKS, 256, 0, stream>>>(
            hbuf, wTt + l * 12288, btp + l * 192, qbuf, kbuf, vbuf, 0);
        temporal_attn_kernel<<<ATTN_BLOCKS, 256, 0, stream>>>(qbuf, kbuf, vbuf, hbuf);
    }
    out_proj_kernel<<<(BB * NNODE * 3 + 255) / 256, 256, 0, stream>>>(
        hbuf, d_in[16], d_in[17], d_out, flag);
}

// Round 5
// 233.042 us; speedup vs baseline: 1.4002x; 1.0421x over previous
//
#include <hip/hip_runtime.h>
#include <hip/hip_bf16.h>

#define HIDN   64
#define NHEADS 8
#define DHEAD  8
#define NLAY   2
#define BB     4
#define SS     12
#define NNODE  512
#define NEDGE  8192
#define XELEMS (BB * SS * NNODE * 3)      // 73728
#define ROWS   (BB * SS * NNODE)          // 24576
#define QSCALE 0.51006967f                // (1/sqrt(8)) * log2(e): exp(x)=exp2(x*log2e)

typedef unsigned short u16;
typedef unsigned int   u32;
typedef __attribute__((ext_vector_type(4))) float f4;   // indexable float4

__device__ __forceinline__ float b2f(u16 u) {
    union { u32 i; float f; } c; c.i = ((u32)u) << 16; return c.f;
}
// decode element i of a raw input tensor (fl=1 -> fp32, fl=0 -> bf16)
__device__ __forceinline__ float ld(const void* p, int i, int fl) {
    return fl ? ((const float*)p)[i] : b2f(((const u16*)p)[i]);
}

// -------- dtype detection FALLBACK (only if in_sizes is ambiguous) -----------
__global__ void detect_kernel(const u16* __restrict__ x, int* __restrict__ flag) {
    int i0 = blockIdx.x * 256 + threadIdx.x;
    int bad = 0;
    for (int i = i0; i < XELEMS; i += 64 * 256) {
        float v = fabsf(b2f(x[i]));
        if (!(v <= 100.f)) bad = 1;   // catches huge AND NaN
    }
    if (bad) atomicOr(flag, 1);       // flag=1 -> inputs are fp32
}

// ---------------- PREP mega-kernel: input_proj + weight pack + mask/CSR ------
// grid = 3072 (input_proj) + 96 (pack) + 1 (mask+csr), 512 threads.
// All three sub-tasks are mutually independent.
struct PrepArgs {
    // input proj
    const void* x; const void* Win; const void* bin; float* h;
    // pack (p=0 spatial, p=1 temporal)
    const void* Wq[2]; const void* bq[2];
    const void* Wk[2]; const void* bk[2];
    const void* Wv[2]; const void* bv[2];
    float* wT[2]; float* bp[2];
    // mask / csr
    const int* ei; int* row_ptr; u16* col_idx;
};
__global__ __launch_bounds__(512) void prep_kernel(PrepArgs a, const int* __restrict__ flagp) {
    __shared__ u32 msk[NNODE * 16];   // 32 KB (only used by last block)
    __shared__ int sc[512];
    int fl = (*flagp != 0);
    int bid = blockIdx.x;
    int tid = threadIdx.x;
    if (bid < 3072) {
        // ---- input projection: h[row][j], raw x @ raw WinT + bin
        int t = bid * 512 + tid;          // row*64 + j
        int row = t >> 6, j = t & 63;
        float x0 = ld(a.x, row * 3, fl);
        float x1 = ld(a.x, row * 3 + 1, fl);
        float x2 = ld(a.x, row * 3 + 2, fl);
        a.h[t] = ld(a.bin, j, fl) + x0 * ld(a.Win, j * 3, fl)
               + x1 * ld(a.Win, j * 3 + 1, fl) + x2 * ld(a.Win, j * 3 + 2, fl);
        return;
    }
    if (bid < 3072 + 96) {
        // ---- weight pack: wT[p][l][phase][j][iloc] linear t = ph*6144 + j*32 + iloc
        int u = (bid - 3072) * 512 + tid;  // 0..49151
        int p = u / 24576;
        int rem = u - p * 24576;
        int l = rem / 12288;
        int t = rem - l * 12288;
        int ph   = (t >= 6144) ? 1 : 0;
        int r2   = t - ph * 6144;
        int j    = r2 >> 5;
        int iloc = r2 & 31;
        int i    = ph * 32 + iloc;
        int c = j >> 6, cc = j & 63;
        const void* W = (c == 0) ? a.Wq[p] : (c == 1) ? a.Wk[p] : a.Wv[p];
        a.wT[p][l * 12288 + t] = ld(W, l * 4096 + cc * 64 + i, fl);
        if (ph == 0 && iloc == 0) {
            const void* B = (c == 0) ? a.bq[p] : (c == 1) ? a.bk[p] : a.bv[p];
            a.bp[p][l * 192 + j] = ld(B, l * 64 + cc, fl);
        }
        return;
    }
    // ---- mask bitset (LDS) + CSR build, one 512-thread block
    for (int i = tid; i < NNODE * 16; i += 512) msk[i] = 0;
    __syncthreads();
    for (int e = tid; e < NEDGE; e += 512) {
        int r = a.ei[e];           // query row
        int m = a.ei[NEDGE + e];   // key col
        atomicOr(&msk[r * 16 + (m >> 5)], 1u << (m & 31));
    }
    __syncthreads();
    int n = tid;   // 0..511
    u32 w[16];
    int d = 0;
#pragma unroll
    for (int i = 0; i < 16; ++i) { w[i] = msk[n * 16 + i]; d += __popc(w[i]); }
    sc[n] = d;
    __syncthreads();
    for (int s = 1; s < 512; s <<= 1) {
        int v = (n >= s) ? sc[n - s] : 0;
        __syncthreads();
        sc[n] += v;
        __syncthreads();
    }
    int excl = sc[n] - d;
    a.row_ptr[n] = excl;
    if (n == 511) a.row_ptr[512] = sc[511];
    int base = excl;
#pragma unroll
    for (int i = 0; i < 16; ++i) {
        u32 m = w[i];
        while (m) {
            int b = __ffs(m) - 1;
            m &= m - 1;
            a.col_idx[base++] = (u16)(i * 32 + b);
        }
    }
}

// ---------------- fused q/k/v GEMM v3: conflict-free W reads -----------------
// block: 32 rows x 192 cols, 256 threads. thread = (wave w = row octet, lane c = col).
// wST stride 34: W reads are b64 pairs, bank start 2c mod 32 -> 2-way = free.
// hS reads wave-uniform (broadcast). Accumulation order identical -> bit-identical.
__global__ __launch_bounds__(256) void qkv_gemm_kernel(
    const float* __restrict__ h, const float* __restrict__ wT,
    const float* __restrict__ bias,
    float* __restrict__ q, float* __restrict__ k, float* __restrict__ v,
    int spatial_layout) {
    __shared__ float hS[32][68];    // [row][i 0..63], pad 68
    __shared__ float wST[192][34];  // per-phase [col j][iloc 0..31], stride 34
    __shared__ float bS[192];
    int t = threadIdx.x;
    int row0 = blockIdx.x * 32;
    // stage hS: fully coalesced float4 loads
    {
        const float4* src = (const float4*)(h + row0 * 64);
        float4 a0 = src[t];
        float4 a1 = src[t + 256];
        int rs = t >> 4, cs = (t & 15) * 4;
        *(float4*)&hS[rs][cs]      = a0;
        *(float4*)&hS[16 + rs][cs] = a1;
    }
    // stage wST phase 0 (linear source thanks to pack layout) + bias
    {
        const float4* src = (const float4*)wT;
#pragma unroll
        for (int kk = 0; kk < 6; ++kk) {
            float4 w4 = src[t + 256 * kk];
            int idx = 4 * (t + 256 * kk);    // = j*32 + iloc
            int j = idx >> 5, il = idx & 31;
            *(float2*)&wST[j][il]     = make_float2(w4.x, w4.y);
            *(float2*)&wST[j][il + 2] = make_float2(w4.z, w4.w);
        }
        if (t < 192) bS[t] = bias[t];
    }
    __syncthreads();
    int c = t & 63, w = t >> 6;
    int rbase = w * 8;
    float acc[3][8];
#pragma unroll
    for (int g = 0; g < 3; ++g) {
        float bb = bS[g * 64 + c];
#pragma unroll
        for (int rr = 0; rr < 8; ++rr) acc[g][rr] = bb;
    }
    // ---- phase 0: i = 0..31
#pragma unroll 2
    for (int i0 = 0; i0 < 32; i0 += 4) {
        f4 hv[8];
#pragma unroll
        for (int rr = 0; rr < 8; ++rr) hv[rr] = *(const f4*)&hS[rbase + rr][i0];
        f4 wv[3];
#pragma unroll
        for (int g = 0; g < 3; ++g) {
            float2 lo = *(const float2*)&wST[g * 64 + c][i0];
            float2 hi = *(const float2*)&wST[g * 64 + c][i0 + 2];
            wv[g] = (f4){lo.x, lo.y, hi.x, hi.y};
        }
#pragma unroll
        for (int ii = 0; ii < 4; ++ii)
#pragma unroll
            for (int g = 0; g < 3; ++g) {
                float wf = wv[g][ii];
#pragma unroll
                for (int rr = 0; rr < 8; ++rr) acc[g][rr] += hv[rr][ii] * wf;
            }
    }
    __syncthreads();
    // stage wST phase 1
    {
        const float4* src = (const float4*)(wT + 6144);
#pragma unroll
        for (int kk = 0; kk < 6; ++kk) {
            float4 w4 = src[t + 256 * kk];
            int idx = 4 * (t + 256 * kk);
            int j = idx >> 5, il = idx & 31;
            *(float2*)&wST[j][il]     = make_float2(w4.x, w4.y);
            *(float2*)&wST[j][il + 2] = make_float2(w4.z, w4.w);
        }
    }
    __syncthreads();
    // ---- phase 1: i = 32..63
#pragma unroll 2
    for (int i0 = 0; i0 < 32; i0 += 4) {
        f4 hv[8];
#pragma unroll
        for (int rr = 0; rr < 8; ++rr) hv[rr] = *(const f4*)&hS[rbase + rr][32 + i0];
        f4 wv[3];
#pragma unroll
        for (int g = 0; g < 3; ++g) {
            float2 lo = *(const float2*)&wST[g * 64 + c][i0];
            float2 hi = *(const float2*)&wST[g * 64 + c][i0 + 2];
            wv[g] = (f4){lo.x, lo.y, hi.x, hi.y};
        }
#pragma unroll
        for (int ii = 0; ii < 4; ++ii)
#pragma unroll
            for (int g = 0; g < 3; ++g) {
                float wf = wv[g][ii];
#pragma unroll
                for (int rr = 0; rr < 8; ++rr) acc[g][rr] += hv[rr][ii] * wf;
            }
    }
    // ---- epilogue: lane-consecutive stores
    if (spatial_layout) {
        int bs = row0 >> 9, n0 = row0 & 511;
        int hd = c >> 3, dh = c & 7;
        long off = ((long)(bs * 8 + hd) * 512 + n0 + rbase) * 8 + dh;
        float* qp = q + off;
        float* kp = k + off;
        float* vp = v + off;
#pragma unroll
        for (int rr = 0; rr < 8; ++rr) {
            qp[rr * 8] = acc[0][rr] * QSCALE;
            kp[rr * 8] = acc[1][rr];
            vp[rr * 8] = acc[2][rr];
        }
    } else {
        int off = (row0 + rbase) * 64 + c;
        float* qp = q + off;
        float* kp = k + off;
        float* vp = v + off;
#pragma unroll
        for (int rr = 0; rr < 8; ++rr) {
            qp[rr * 64] = acc[0][rr];
            kp[rr * 64] = acc[1][rr];
            vp[rr * 64] = acc[2][rr];
        }
    }
}

// ---------------- spatial attention: SPARSE (avg degree 16/512) --------------
__global__ __launch_bounds__(256) void spatial_attn_kernel(
    const float* __restrict__ qh, const float* __restrict__ kh, const float* __restrict__ vh,
    const int* __restrict__ row_ptr, const u16* __restrict__ col_idx,
    float* __restrict__ h) {
    __shared__ __align__(16) float Ks[NNODE][8];   // 16 KB
    __shared__ __align__(16) float Vs[NNODE][8];   // 16 KB
    int bxx = blockIdx.x;
    int pair = bxx >> 1, halfq = bxx & 1;
    int bs = pair >> 3, hd = pair & 7;      // bs = b*S+s in [0,48)
    const float* kp = kh + pair * (NNODE * 8);
    const float* vp = vh + pair * (NNODE * 8);
    int t = threadIdx.x;
#pragma unroll
    for (int i = 0; i < 2; ++i) {
        int r = t + 256 * i;
        float4 k0 = *(const float4*)(kp + r * 8);
        float4 k1 = *(const float4*)(kp + r * 8 + 4);
        float4 v0 = *(const float4*)(vp + r * 8);
        float4 v1 = *(const float4*)(vp + r * 8 + 4);
        *(float4*)&Ks[r][0] = k0; *(float4*)&Ks[r][4] = k1;
        *(float4*)&Vs[r][0] = v0; *(float4*)&Vs[r][4] = v1;
    }
    __syncthreads();
    int n = halfq * 256 + t;
    const float* qp = qh + (pair * NNODE + n) * 8;
    float4 qa = *(const float4*)qp;
    float4 qc = *(const float4*)(qp + 4);
    int e0 = row_ptr[n], e1 = row_ptr[n + 1];
    float l = 0.f;
    float o0=0.f,o1=0.f,o2=0.f,o3=0.f,o4=0.f,o5=0.f,o6=0.f,o7=0.f;
    for (int e = e0; e < e1; ++e) {
        int m = col_idx[e];
        float4 ka = *(const float4*)&Ks[m][0];
        float4 kc = *(const float4*)&Ks[m][4];
        float s = qa.x*ka.x + qa.y*ka.y + qa.z*ka.z + qa.w*ka.w
                + qc.x*kc.x + qc.y*kc.y + qc.z*kc.z + qc.w*kc.w;
        float p = exp2f(s);          // q prescaled by (1/sqrt8)*log2e
        l += p;
        float4 va = *(const float4*)&Vs[m][0];
        float4 vc = *(const float4*)&Vs[m][4];
        o0 += p*va.x; o1 += p*va.y; o2 += p*va.z; o3 += p*va.w;
        o4 += p*vc.x; o5 += p*vc.y; o6 += p*vc.z; o7 += p*vc.w;
    }
    if (e1 == e0) {                  // fully-masked row: uniform mean(V)
        for (int m = 0; m < NNODE; ++m) {
            o0 += Vs[m][0]; o1 += Vs[m][1]; o2 += Vs[m][2]; o3 += Vs[m][3];
            o4 += Vs[m][4]; o5 += Vs[m][5]; o6 += Vs[m][6]; o7 += Vs[m][7];
        }
        l = (float)NNODE;
    }
    float inv = 1.f / l;
    float* op = h + (bs * NNODE + n) * HIDN + hd * 8;
    *(float4*)op       = make_float4(o0*inv, o1*inv, o2*inv, o3*inv);
    *(float4*)(op + 4) = make_float4(o4*inv, o5*inv, o6*inv, o7*inv);
}

// ---------------- temporal attention v2: LDS-staged K/V (kills 12x re-read) --
// grid 256 = (b [4]) x (node chunk of 8 [64]); 768 threads = (sq, nloc, hd).
// K/V for all 12 timesteps staged once; per-output reads from LDS.
// Same expression/accumulation order as v1 -> bit-identical.
__global__ __launch_bounds__(768) void temporal_attn_kernel(
    const float* __restrict__ q, const float* __restrict__ k, const float* __restrict__ v,
    float* __restrict__ h) {
    __shared__ float Ks2[SS][8][68];   // 26 KB
    __shared__ float Vs2[SS][8][68];   // 26 KB
    int b  = blockIdx.x >> 6;
    int n0 = (blockIdx.x & 63) * 8;
    int t = threadIdx.x;
    // stage: 1536 float4 per tensor; 768 threads -> 2 each
#pragma unroll
    for (int j = 0; j < 2; ++j) {
        int fid = t + 768 * j;            // 0..1535
        int tt  = fid >> 7;
        int rem = fid & 127;
        int nl  = rem >> 4;
        int dq  = rem & 15;
        long goff = ((long)((b * SS + tt) * NNODE) + n0 + nl) * HIDN + dq * 4;
        *(float4*)&Ks2[tt][nl][dq * 4] = *(const float4*)(k + goff);
        *(float4*)&Vs2[tt][nl][dq * 4] = *(const float4*)(v + goff);
    }
    __syncthreads();
    int hd = t & 7, nl = (t >> 3) & 7, sq = t >> 6;   // sq 0..11
    const float* qp = q + ((long)((b * SS + sq) * NNODE) + n0 + nl) * HIDN + hd * 8;
    float4 qa = *(const float4*)qp;
    float4 qc = *(const float4*)(qp + 4);
    float s[SS];
#pragma unroll
    for (int tt = 0; tt < SS; ++tt) {
        float4 ka = *(const float4*)&Ks2[tt][nl][hd * 8];
        float4 kc = *(const float4*)&Ks2[tt][nl][hd * 8 + 4];
        s[tt] = (qa.x * ka.x + qa.y * ka.y + qa.z * ka.z + qa.w * ka.w +
                 qc.x * kc.x + qc.y * kc.y + qc.z * kc.z + qc.w * kc.w) * QSCALE;
    }
    float mx = s[0];
#pragma unroll
    for (int tt = 1; tt < SS; ++tt) mx = fmaxf(mx, s[tt]);
    float l = 0.f;
#pragma unroll
    for (int tt = 0; tt < SS; ++tt) { s[tt] = exp2f(s[tt] - mx); l += s[tt]; }
    float a0 = 0.f, a1 = 0.f, a2 = 0.f, a3 = 0.f, a4 = 0.f, a5 = 0.f, a6 = 0.f, a7 = 0.f;
#pragma unroll
    for (int tt = 0; tt < SS; ++tt) {
        float4 va = *(const float4*)&Vs2[tt][nl][hd * 8];
        float4 vc = *(const float4*)&Vs2[tt][nl][hd * 8 + 4];
        float e = s[tt];
        a0 += e * va.x; a1 += e * va.y; a2 += e * va.z; a3 += e * va.w;
        a4 += e * vc.x; a5 += e * vc.y; a6 += e * vc.z; a7 += e * vc.w;
    }
    float inv = 1.f / l;
    float* op = h + ((long)((b * SS + sq) * NNODE) + n0 + nl) * HIDN + hd * 8;
    *(float4*)op       = make_float4(a0 * inv, a1 * inv, a2 * inv, a3 * inv);
    *(float4*)(op + 4) = make_float4(a4 * inv, a5 * inv, a6 * inv, a7 * inv);
}

// ---------------- output projection: h[:, S-1] @ raw WoutT + raw bout --------
__global__ void out_proj_kernel(const float* __restrict__ h, const void* __restrict__ W,
                                const void* __restrict__ b, void* __restrict__ out,
                                const int* __restrict__ flagp) {
    int fl = (*flagp != 0);
    int t = blockIdx.x * blockDim.x + threadIdx.x;
    if (t >= BB * NNODE * 3) return;
    int c  = t % 3;
    int bn = t / 3;
    int n  = bn & (NNODE - 1);
    int bb = bn >> 9;
    const float* hp = h + ((bb * SS + (SS - 1)) * NNODE + n) * HIDN;
    float a = ld(b, c, fl);
#pragma unroll
    for (int i = 0; i < HIDN; i += 4) {
        float4 h4 = *(const float4*)(hp + i);
        a += h4.x * ld(W, c * 64 + i,     fl) + h4.y * ld(W, c * 64 + i + 1, fl)
           + h4.z * ld(W, c * 64 + i + 2, fl) + h4.w * ld(W, c * 64 + i + 3, fl);
    }
    if (fl) ((float*)out)[t] = a;
    else    ((__hip_bfloat16*)out)[t] = __float2bfloat16(a);
}

extern "C" void kernel_launch(void* const* d_in, const int* in_sizes, int n_in,
                              void* d_out, int out_size, void* d_ws, size_t ws_size,
                              hipStream_t stream) {
    const int* ei = (const int*)d_in[1];

    float* ws = (float*)d_ws;
    int*   flag    = (int*)ws;                    // 64 floats reserved
    int*   row_ptr = (int*)(ws + 64);             // 513 ints (reserve 576)
    u16*   col_idx = (u16*)(ws + 640);            // 8192 u16 (4096 float slots)
    float* wTs   = ws + 640 + 4096;               // 2*12288
    float* wTt   = wTs + 24576;                   // 2*12288
    float* bsp   = wTt + 24576;                   // 2*192
    float* btp   = bsp + 384;                     // 2*192
    float* hbuf  = btp + 384;                     // ROWS*64 each
    float* qbuf  = hbuf + ROWS * HIDN;
    float* kbuf  = qbuf + ROWS * HIDN;
    float* vbuf  = kbuf + ROWS * HIDN;

    // dtype from host-visible byte sizes; runtime-detect only if ambiguous
    int flv = -1;
    if (in_sizes) {
        if (in_sizes[0] == XELEMS * 2) flv = 0;        // bf16
        else if (in_sizes[0] == XELEMS * 4) flv = 1;   // fp32
    }
    if (flv >= 0) {
        (void)hipMemsetAsync(flag, flv, sizeof(int), stream);
    } else {
        (void)hipMemsetAsync(flag, 0, sizeof(int), stream);
        detect_kernel<<<64, 256, 0, stream>>>((const u16*)d_in[0], flag);
    }

    PrepArgs pr;
    pr.x = d_in[0]; pr.Win = d_in[2]; pr.bin = d_in[3]; pr.h = hbuf;
    pr.Wq[0] = d_in[4];  pr.bq[0] = d_in[5];
    pr.Wk[0] = d_in[6];  pr.bk[0] = d_in[7];
    pr.Wv[0] = d_in[8];  pr.bv[0] = d_in[9];
    pr.Wq[1] = d_in[10]; pr.bq[1] = d_in[11];
    pr.Wk[1] = d_in[12]; pr.bk[1] = d_in[13];
    pr.Wv[1] = d_in[14]; pr.bv[1] = d_in[15];
    pr.wT[0] = wTs; pr.bp[0] = bsp;
    pr.wT[1] = wTt; pr.bp[1] = btp;
    pr.ei = ei; pr.row_ptr = row_ptr; pr.col_idx = col_idx;
    prep_kernel<<<3072 + 96 + 1, 512, 0, stream>>>(pr, flag);

    const int GEMM_BLOCKS = ROWS / 32;                       // 768
    for (int l = 0; l < NLAY; ++l) {
        // spatial
        qkv_gemm_kernel<<<GEMM_BLOCKS, 256, 0, stream>>>(
            hbuf, wTs + l * 12288, bsp + l * 192, qbuf, kbuf, vbuf, 1);
        spatial_attn_kernel<<<BB * SS * NHEADS * 2, 256, 0, stream>>>(
            qbuf, kbuf, vbuf, row_ptr, col_idx, hbuf);
        // temporal
        qkv_gemm_kernel<<<GEMM_BLOCKS, 256, 0, stream>>>(
            hbuf, wTt + l * 12288, btp + l * 192, qbuf, kbuf, vbuf, 0);
        temporal_attn_kernel<<<BB * (NNODE / 8), 768, 0, stream>>>(
            qbuf, kbuf, vbuf, hbuf);
    }
    out_proj_kernel<<<(BB * NNODE * 3 + 255) / 256, 256, 0, stream>>>(
        hbuf, d_in[16], d_in[17], d_out, flag);
}